// Round 12
// baseline (2021.988 us; speedup 1.0000x reference)
//
#include <hip/hip_runtime.h>
#include <hip/hip_bf16.h>

// SNN: B=256, IN=1024, HID=2048, OUT=10, T=100, decay=0.9, thr=1.0, reset=0.
// Layer-pipelined: GEMM1(all t) -> LIF scan -> GEMM2(all t) -> scan -> GEMM3 -> scan.
// Hidden GEMMs: i8 Ozaki split, 4 digit planes of round(w*2^31) (exact split;
// i32 MFMA accumulation exact).
// Round-26 (vs r25 REGRESSION 1984us / r24 best 811us):
//  - r25's inner loop KEPT (2x2 waves of 64 rows x 16 cols; 4 ds_read_b128
//    per K-step each feeding 4 MFMAs -> LDS-read demand halved vs r24's
//    76%-busy LDS pipe). r25's REGRESSION CAUSE FIXED: its per-wave 16-col
//    C strips (64B) caused partial-line RMW (WRITE 205MB->2.5GB, FETCH
//    77->873MB). Now: epilogue LDS exchange - wc=1 waves deposit finished
//    fp32 values (8KB in dead blds; extra barrier drains tail stages),
//    wc=0 waves write FULL 32-col rows (2 adjacent 64B stores per row from
//    ONE wave = r24's proven full-line pattern).
//    Results bit-identical -> absmax must stay exactly 0.01025391.
//  - KEPT from r24: 4-slot ring 4 blk/CU, pair-barrier vmcnt discipline,
//    gemm_out double-buffer, lif_scan 8-deep prefetch, LDS-staged bitpack,
//    i8-MFMA gemm_out, fp32 C single chunk (CH=100), cvt_who_i8,
//    8KB-region cvt_w_i8 swizzle.

#define B 256
#define IN_DIM 1024
#define HID 2048
#define OUT_DIM 10
#define T_STEPS 100
#define NCH 4
#define RT (T_STEPS * B)   // 25600 global rows

typedef unsigned long long ull;
typedef int v4i __attribute__((ext_vector_type(4)));

// ---- weight fp32 -> 4 signed base-256 digit planes of round(w*2^31),
// swizzled to MFMA fragment order: region per (nb32, wb) = 8192 B, fragment
// (c,ct) at (c*2+ct)*1024, byte lane*16+jj, lane=lk*16+li,
// n = nb32*32 + ct*16 + li, k = wb*64 + lk*16 + jj.
// One thread: 4 consecutive k (same n) -> coalesced W loads, dword stores. ----
template<int K>
__global__ __launch_bounds__(256) void cvt_w_i8(
    const float* __restrict__ W, signed char* __restrict__ Bq)
{
    constexpr int WPR = K / 64;
    size_t id = (size_t)blockIdx.x * 256 + threadIdx.x;
    if (id >= (size_t)(K / 4) * HID) return;
    int n  = (int)(id % HID);
    int kg = (int)(id / HID);
    int k0 = kg * 4;                                  // jj multiple of 4
    signed char dig[4][4];                            // [plane][i]
#pragma unroll
    for (int i = 0; i < 4; ++i) {
        double w = (double)W[(size_t)(k0 + i) * HID + n];
        long long V = __double2ll_rn(w * 2147483648.0);   // w * 2^31
#pragma unroll
        for (int c = 0; c < 3; ++c) {
            int r = (int)(signed char)(V & 0xFF);     // balanced digit [-128,127]
            dig[c][i] = (signed char)r;
            V = (V - r) >> 8;
        }
        dig[3][i] = (signed char)V;                   // |V| <= ~70
    }
    int wb = k0 >> 6, lk = (k0 >> 4) & 3, jj = k0 & 15;
    int nb32 = n >> 5, ct = (n >> 4) & 1, li = n & 15;
    int lane = lk * 16 + li;
    size_t base = ((size_t)nb32 * WPR + wb) * 8192 + (size_t)lane * 16 + jj;
#pragma unroll
    for (int c = 0; c < 4; ++c) {
        int pc = c * 2 + ct;                          // c=3 -> 6+ct
        unsigned pk = (unsigned)(unsigned char)dig[c][0]
                    | ((unsigned)(unsigned char)dig[c][1] << 8)
                    | ((unsigned)(unsigned char)dig[c][2] << 16)
                    | ((unsigned)(unsigned char)dig[c][3] << 24);
        *reinterpret_cast<unsigned*>(Bq + base + (size_t)pc * 1024) = pk;
    }
}

// ---- output weights fp32 -> 4 i8 digit planes (exact), MFMA fragment order.
// Region per w (64 k): 4 planes x 1024 B; byte = plane*1024 + lane*16 + jj.
// k = w*64 + lk*16 + jj, col = li (cols 10..15 zero-padded). ----
__global__ __launch_bounds__(256) void cvt_who_i8(
    const float* __restrict__ who, signed char* __restrict__ Bq3)
{
    int id = blockIdx.x * 256 + threadIdx.x;      // 32 w x 64 lane x 4 jj-groups
    if (id >= 32 * 64 * 4) return;
    int jg = id & 3;
    int lane = (id >> 2) & 63;
    int w = id >> 8;
    int li = lane & 15, lk = lane >> 4;
    signed char dig[4][4];
#pragma unroll
    for (int i = 0; i < 4; ++i) {
        int jj = jg * 4 + i;
        int k = w * 64 + lk * 16 + jj;
        double x = (li < OUT_DIM) ? (double)who[(size_t)k * OUT_DIM + li] : 0.0;
        long long V = __double2ll_rn(x * 2147483648.0);
#pragma unroll
        for (int c = 0; c < 3; ++c) {
            int r = (int)(signed char)(V & 0xFF);
            dig[c][i] = (signed char)r;
            V = (V - r) >> 8;
        }
        dig[3][i] = (signed char)V;
    }
    size_t base = (size_t)w * 4096 + (size_t)lane * 16 + jg * 4;
#pragma unroll
    for (int c = 0; c < 4; ++c) {
        unsigned pk = (unsigned)(unsigned char)dig[c][0]
                    | ((unsigned)(unsigned char)dig[c][1] << 8)
                    | ((unsigned)(unsigned char)dig[c][2] << 16)
                    | ((unsigned)(unsigned char)dig[c][3] << 24);
        *reinterpret_cast<unsigned*>(Bq3 + base + (size_t)c * 1024) = pk;
    }
}

// ---- bit-pack input spikes -> TRANSPOSED XbitsT[w][t*256+b] ----
// Coalesced: each wave stages [64 i][<=32 t] fp32 tiles into LDS (flat copy,
// pad-33 row stride -> conflict-free column reads), then ballots from LDS.
__global__ __launch_bounds__(256) void bitpack_input(
    const float* __restrict__ inp, ull* __restrict__ XbitsT)
{
    __shared__ float sb[4][64][33];   // 33.8 KB
    const int wv = threadIdx.x >> 6;
    const int lane = threadIdx.x & 63;
    const int g = blockIdx.x * 4 + wv;
    const int b = g >> 4;
    const int ig = g & 15;
    const float* __restrict__ src = inp + ((size_t)b * IN_DIM + ig * 64) * T_STEPS;
    ull* __restrict__ dst = XbitsT + (size_t)ig * RT + b;

#pragma unroll
    for (int tc = 0; tc < 4; ++tc) {
        const int t0 = tc * 32;
        if (tc < 3) {
#pragma unroll
            for (int f4 = 0; f4 < 32; ++f4) {
                int f = f4 * 64 + lane;
                int ii = f >> 5, tt = f & 31;
                sb[wv][ii][tt] = src[ii * T_STEPS + t0 + tt];
            }
        } else {
#pragma unroll
            for (int f4 = 0; f4 < 4; ++f4) {
                int f = f4 * 64 + lane;
                int ii = f >> 2, tt = f & 3;
                sb[wv][ii][tt] = src[ii * T_STEPS + t0 + tt];
            }
        }
        __syncthreads();
        const int len = (tc < 3) ? 32 : 4;
        for (int tt = 0; tt < len; ++tt) {
            float v = sb[wv][lane][tt];
            ull m = __ballot(v > 0.5f);
            if (lane == 0) dst[(size_t)(t0 + tt) * B] = m;
        }
        __syncthreads();
    }
}

// ---- i8 Ozaki bit-GEMM: 64x16 waves, 4-slot ring, LDS epilogue exchange ----
// Block: 128 rows x 32 cols as 2x2 waves of 64 rows x 16 cols.
// Grid: x = rows/128, y = HID/32. row_base = t0*B (global row offset).
// Per K-step per wave: 4 ds_read_b128 (own col-half), each feeds 4 MFMAs.
// Per pair per wave: 4 stage + 8 mask loads; "s_waitcnt vmcnt(8); s_barrier".
// Epilogue: wc=1 -> LDS; wc=0 writes full 32-col rows (full 128B lines).
template<int K>
__global__ __launch_bounds__(256, 4) void gemm_i8(
    const ull* __restrict__ bitsT, int row_base,
    const signed char* __restrict__ Bq, float* __restrict__ C)
{
    constexpr int WPR = K / 64;          // 16 (L1) / 32 (L2)
    constexpr int NP  = WPR / 2;         // pairs: 8 / 16  (even)
    __shared__ __align__(16) signed char blds[4][8192];   // 32 KB -> 4 blk/CU

    const int tid = threadIdx.x;
    const int lane = tid & 63;
    const int wv = __builtin_amdgcn_readfirstlane(tid >> 6);
    const int wr = wv >> 1;                               // row half 0/1
    const int wc = wv & 1;                                // col half 0/1
    const int row0 = blockIdx.x * 128;                    // local row base
    const int c0 = blockIdx.y * 32;
    const int li = lane & 15;
    const int lk = lane >> 4;
    const int sh = lk * 16;
    const int r0l = wr * 64;

    const signed char* __restrict__ bsrc = Bq + (size_t)blockIdx.y * WPR * 8192;
    // lane li (replicated over lk) holds mask of row row0 + wr*64 + g*16 + li
    const ull* __restrict__ mp = bitsT + (row_base + row0 + r0l + li);

    // stage B(w) into ring slot: 8 segments of 1 KB, 2 per wave (async to LDS)
    auto stage_b = [&](int w, int slot) {
        const signed char* src = bsrc + (size_t)w * 8192 + lane * 16;
        signed char* db = &blds[0][0] + slot * 8192;
        __builtin_amdgcn_global_load_lds(
            (const __attribute__((address_space(1))) unsigned int*)(src + wv * 1024),
            (__attribute__((address_space(3))) unsigned int*)(db + wv * 1024), 16, 0, 0);
        __builtin_amdgcn_global_load_lds(
            (const __attribute__((address_space(1))) unsigned int*)(src + (wv + 4) * 1024),
            (__attribute__((address_space(3))) unsigned int*)(db + (wv + 4) * 1024), 16, 0, 0);
    };

    // prologue: stage pair 0 (w=0,1 -> slots 0,1); masks for pairs 0,1 (w=0..3)
    stage_b(0, 0);
    stage_b(1, 1);
    ull r[4][4];                         // [w&3][row-group]
#pragma unroll
    for (int u = 0; u < 4; ++u)
#pragma unroll
        for (int g = 0; g < 4; ++g)
            r[u][g] = mp[(size_t)u * RT + g * 16];
    __syncthreads();   // full drain once (prologue)

    v4i acc[4][NCH];                     // [row-group][plane] = 64 VGPR
#pragma unroll
    for (int g = 0; g < 4; ++g)
#pragma unroll
        for (int c = 0; c < NCH; ++c) acc[g][c] = (v4i){0, 0, 0, 0};

    // Ring: pair P (parity q) reads slots {2q,2q+1}; stages w=2P+2,2P+3 into
    // {2-2q,3-2q} (consumed at P-1; the P-1 -> P barrier protects them).
    // Mask ring: slot u=w&3; refill with w+4 (consumed at pair P+2, stays in
    // flight across the vmcnt(8)). Tail stages/masks wrap to dummy-valid w.
#pragma unroll 1
    for (int p2 = 0; p2 < NP; p2 += 2) {  // 2 pairs per outer iter (idx const)
#pragma unroll
        for (int pp = 0; pp < 2; ++pp) {
            const int w0 = (p2 + pp) * 2;           // first w of pair
            const int q  = pp;                      // pair parity (p2 even)
            const int s0 = 2 * q, s1 = 2 * q + 1;   // consume slots
            const int tA = 2 - 2 * q, tB = 3 - 2 * q;   // stage slots
            const int u0 = 2 * q, u1 = 2 * q + 1;   // mask slots

            // stage NEXT pair FIRST
            int wn0 = w0 + 2; if (wn0 >= WPR) wn0 -= WPR;   // tail: dummy-valid
            int wn1 = w0 + 3; if (wn1 >= WPR) wn1 -= WPR;
            stage_b(wn0, tA);
            stage_b(wn1, tB);
            int wm0 = w0 + 4; if (wm0 >= WPR) wm0 -= WPR;
            int wm1 = w0 + 5; if (wm1 >= WPR) wm1 -= WPR;

            // ---- K-step A (w0), slot s0 ----
            {
                v4i a[4];
#pragma unroll
                for (int g = 0; g < 4; ++g) {
                    unsigned s = (unsigned)(r[u0][g] >> sh) & 0xFFFFu;
#pragma unroll
                    for (int d = 0; d < 4; ++d)
                        a[g][d] = (int)((((s >> (4 * d)) & 0xFu) * 0x00204081u) & 0x01010101u);
                }
#pragma unroll
                for (int g = 0; g < 4; ++g)          // refill after expand
                    r[u0][g] = mp[(size_t)wm0 * RT + g * 16];
                const signed char* bb = &blds[0][0] + s0 * 8192 + lane * 16;
                __builtin_amdgcn_s_setprio(1);
#pragma unroll
                for (int c = 0; c < NCH; ++c) {
                    v4i b = *(const v4i*)(bb + (c * 2 + wc) * 1024);
#pragma unroll
                    for (int g = 0; g < 4; ++g)
                        acc[g][c] = __builtin_amdgcn_mfma_i32_16x16x64_i8(a[g], b, acc[g][c], 0, 0, 0);
                }
                __builtin_amdgcn_s_setprio(0);
            }
            // ---- K-step B (w0+1), slot s1 ----
            {
                v4i a[4];
#pragma unroll
                for (int g = 0; g < 4; ++g) {
                    unsigned s = (unsigned)(r[u1][g] >> sh) & 0xFFFFu;
#pragma unroll
                    for (int d = 0; d < 4; ++d)
                        a[g][d] = (int)((((s >> (4 * d)) & 0xFu) * 0x00204081u) & 0x01010101u);
                }
#pragma unroll
                for (int g = 0; g < 4; ++g)
                    r[u1][g] = mp[(size_t)wm1 * RT + g * 16];
                const signed char* bb = &blds[0][0] + s1 * 8192 + lane * 16;
                __builtin_amdgcn_s_setprio(1);
#pragma unroll
                for (int c = 0; c < NCH; ++c) {
                    v4i b = *(const v4i*)(bb + (c * 2 + wc) * 1024);
#pragma unroll
                    for (int g = 0; g < 4; ++g)
                        acc[g][c] = __builtin_amdgcn_mfma_i32_16x16x64_i8(a[g], b, acc[g][c], 0, 0, 0);
                }
                __builtin_amdgcn_s_setprio(0);
            }

            // drain this pair's 4 stages (+ previous pair's leftover masks);
            // the 8 mask refills (consumed at P+2) stay in flight
            __asm__ __volatile__("s_waitcnt vmcnt(8)\n\ts_barrier" ::: "memory");
        }
    }

    // ---- epilogue: exact recombination + cross-wave col-half exchange ----
    // V = (((S3<<8)+S2)<<8+S1)<<8+S0; |V| < 2^43. fp32 conversion BEFORE
    // exchange (bit-identical to direct store). wc=1 -> LDS (8KB of dead
    // blds); wc=0 writes full 32-col rows = full 128B lines from one wave.
    float fv[4][4];
#pragma unroll
    for (int g = 0; g < 4; ++g) {
#pragma unroll
        for (int rr = 0; rr < 4; ++rr) {
            long long V = (long long)acc[g][3][rr];
            V = (V << 8) + (long long)acc[g][2][rr];
            V = (V << 8) + (long long)acc[g][1][rr];
            V = (V << 8) + (long long)acc[g][0][rr];
            fv[g][rr] = (float)((double)V * 0x1p-31);
        }
    }
    __syncthreads();   // drains tail stage loads before blds reuse
    float* __restrict__ xch = (float*)&blds[0][0];   // [2 wr][16 g*4+rr][64 lane]
    if (wc == 1) {
#pragma unroll
        for (int g = 0; g < 4; ++g)
#pragma unroll
            for (int rr = 0; rr < 4; ++rr)
                xch[(wr * 16 + g * 4 + rr) * 64 + lane] = fv[g][rr];
    }
    __syncthreads();
    if (wc == 0) {
#pragma unroll
        for (int g = 0; g < 4; ++g) {
#pragma unroll
            for (int rr = 0; rr < 4; ++rr) {
                float hi = xch[(wr * 16 + g * 4 + rr) * 64 + lane];
                size_t base = (size_t)(row0 + r0l + g * 16 + lk * 4 + rr) * HID + c0;
                C[base + li] = fv[g][rr];
                C[base + 16 + li] = hi;
            }
        }
    }
}

// ---- output bit-GEMM via i8 MFMA: 16-col tile (10 used), 4 exact planes ----
// Block: 256 rows, 4 waves (wave = 64 rows x 16 cols). Grid: rows/256.
// Latency-exposed (0.4 blk/CU) -> masks+B double-buffered one w ahead.
__global__ __launch_bounds__(256) void gemm_out(
    const ull* __restrict__ bitsT, int row_base,
    const signed char* __restrict__ Bq3, double* __restrict__ C3)
{
    const int lane = threadIdx.x & 63;
    const int wv = threadIdx.x >> 6;
    const int li = lane & 15;
    const int lk = lane >> 4;
    const int sh = lk * 16;
    const int row0 = blockIdx.x * 256 + wv * 64;
    const ull* __restrict__ mp = bitsT + (row_base + row0 + li);

    v4i acc[4][NCH];   // [row-group][plane]
#pragma unroll
    for (int g = 0; g < 4; ++g)
#pragma unroll
        for (int c = 0; c < NCH; ++c) acc[g][c] = (v4i){0, 0, 0, 0};

    ull m[2][4];
    v4i b[2][NCH];
    // prologue: load w=0 into buf 0
#pragma unroll
    for (int g = 0; g < 4; ++g) m[0][g] = mp[(size_t)0 * RT + g * 16];
    {
        const v4i* __restrict__ bp = (const v4i*)(Bq3 + (size_t)lane * 16);
#pragma unroll
        for (int c = 0; c < NCH; ++c) b[0][c] = bp[c * 64];
    }

#pragma unroll 2
    for (int w = 0; w < 32; ++w) {
        const int cur = w & 1, nxt = cur ^ 1;
        if (w < 31) {   // prefetch w+1 into nxt
#pragma unroll
            for (int g = 0; g < 4; ++g) m[nxt][g] = mp[(size_t)(w + 1) * RT + g * 16];
            const v4i* __restrict__ bp =
                (const v4i*)(Bq3 + (size_t)(w + 1) * 4096 + (size_t)lane * 16);
#pragma unroll
            for (int c = 0; c < NCH; ++c) b[nxt][c] = bp[c * 64];
        }
#pragma unroll
        for (int g = 0; g < 4; ++g) {
            unsigned s = (unsigned)(m[cur][g] >> sh) & 0xFFFFu;
            v4i a;
#pragma unroll
            for (int d = 0; d < 4; ++d)
                a[d] = (int)((((s >> (4 * d)) & 0xFu) * 0x00204081u) & 0x01010101u);
#pragma unroll
            for (int c = 0; c < NCH; ++c)
                acc[g][c] = __builtin_amdgcn_mfma_i32_16x16x64_i8(a, b[cur][c], acc[g][c], 0, 0, 0);
        }
    }

    if (li < OUT_DIM) {
#pragma unroll
        for (int g = 0; g < 4; ++g) {
#pragma unroll
            for (int rr = 0; rr < 4; ++rr) {
                long long V = (long long)acc[g][3][rr];
                V = (V << 8) + (long long)acc[g][2][rr];
                V = (V << 8) + (long long)acc[g][1][rr];
                V = (V << 8) + (long long)acc[g][0][rr];
                C3[(size_t)(row0 + g * 16 + lk * 4 + rr) * OUT_DIM + li] =
                    (double)V * 0x1p-31;
            }
        }
    }
}

// ---- LIF scan for a hidden layer; 8-deep load prefetch ----
__global__ __launch_bounds__(256) void lif_scan(
    const float* __restrict__ C, double* __restrict__ vstate,
    ull* __restrict__ SbitsT, int row_base, int Tl, int first)
{
    int g = blockIdx.x * 4 + (threadIdx.x >> 6);
    int lane = threadIdx.x & 63;
    int b = g >> 5;
    int ng = g & 31;
    int n = ng * 64 + lane;
    const float* __restrict__ Cp = C + (size_t)b * HID + n;
    ull* __restrict__ Sp = SbitsT + (size_t)ng * RT + row_base + b;
    double v = first ? 0.0 : vstate[(size_t)b * HID + n];
    int tl = 0;
    for (; tl + 8 <= Tl; tl += 8) {
        float cc[8];
#pragma unroll
        for (int i = 0; i < 8; ++i)
            cc[i] = Cp[(size_t)(tl + i) * (B * HID)];
#pragma unroll
        for (int i = 0; i < 8; ++i) {
            v = v * 0.9 + (double)cc[i];
            bool s = (v >= 1.0);
            if (s) v = 0.0;
            ull mask = __ballot(s);
            if (lane == 0) Sp[(size_t)(tl + i) * B] = mask;
        }
    }
    for (; tl < Tl; ++tl) {
        double c = (double)Cp[(size_t)tl * (B * HID)];
        v = v * 0.9 + c;
        bool s = (v >= 1.0);
        if (s) v = 0.0;
        ull mask = __ballot(s);
        if (lane == 0) Sp[(size_t)tl * B] = mask;
    }
    vstate[(size_t)b * HID + n] = v;
}

// ---- output LIF scan + rate accumulation; 4-deep prefetch ----
__global__ __launch_bounds__(256) void lif_out(
    const double* __restrict__ C3, double* __restrict__ vstate,
    int* __restrict__ cnt_state, float* __restrict__ out, int Tl, int first)
{
    int tid = blockIdx.x * 256 + threadIdx.x;
    if (tid >= B * OUT_DIM) return;
    int b = tid / OUT_DIM, o = tid % OUT_DIM;
    const double* __restrict__ Cp = C3 + (size_t)b * OUT_DIM + o;
    double v = first ? 0.0 : vstate[tid];
    int cnt = first ? 0 : cnt_state[tid];
    int tl = 0;
    for (; tl + 4 <= Tl; tl += 4) {
        double c0 = Cp[(size_t)(tl + 0) * (B * OUT_DIM)];
        double c1 = Cp[(size_t)(tl + 1) * (B * OUT_DIM)];
        double c2 = Cp[(size_t)(tl + 2) * (B * OUT_DIM)];
        double c3 = Cp[(size_t)(tl + 3) * (B * OUT_DIM)];
#pragma unroll
        for (int i = 0; i < 4; ++i) {
            double cc = (i == 0) ? c0 : (i == 1) ? c1 : (i == 2) ? c2 : c3;
            v = v * 0.9 + cc;
            if (v >= 1.0) { cnt++; v = 0.0; }
        }
    }
    for (; tl < Tl; ++tl) {
        double c = Cp[(size_t)tl * (B * OUT_DIM)];
        v = v * 0.9 + c;
        if (v >= 1.0) { cnt++; v = 0.0; }
    }
    vstate[tid] = v;
    cnt_state[tid] = cnt;
    out[tid] = (float)((double)cnt / (double)T_STEPS);
}

extern "C" void kernel_launch(void* const* d_in, const int* in_sizes, int n_in,
                              void* d_out, int out_size, void* d_ws, size_t ws_size,
                              hipStream_t stream) {
    const float* inp = (const float*)d_in[0];   // [256,1024,100]
    const float* wih = (const float*)d_in[1];   // [1024,2048]
    const float* whh = (const float*)d_in[2];   // [1,2048,2048]
    const float* who = (const float*)d_in[3];   // [2048,10]
    float* out = (float*)d_out;                 // [256,10]

    // ---- workspace layout ----
    unsigned char* p = (unsigned char*)d_ws;
    auto alloc = [&](size_t sz) -> void* {
        void* r = (void*)p;
        p += (sz + 255) & ~(size_t)255;
        return r;
    };
    signed char* Bq1 = (signed char*)alloc((size_t)NCH * HID * IN_DIM + 4096); // 8.4 MB
    signed char* Bq2 = (signed char*)alloc((size_t)NCH * HID * HID + 4096);    // 16.8 MB
    signed char* Bq3 = (signed char*)alloc((size_t)32 * 4096 + 4096);          // 132 KB
    ull* XbitsT = (ull*)alloc((size_t)16 * RT * 8);        // 3.3 MB
    ull* S1T    = (ull*)alloc((size_t)32 * RT * 8);        // 6.6 MB
    ull* S2T    = (ull*)alloc((size_t)32 * RT * 8);        // 6.6 MB
    double* v1 = (double*)alloc((size_t)B * HID * 8);
    double* v2 = (double*)alloc((size_t)B * HID * 8);
    double* vo = (double*)alloc((size_t)B * OUT_DIM * 8);
    int* cnts  = (int*)alloc((size_t)B * OUT_DIM * 4);

    size_t used = (size_t)(p - (unsigned char*)d_ws);
    size_t remain = (ws_size > used) ? (ws_size - used) : 0;
    size_t per_t = (size_t)B * HID * 4 + (size_t)B * OUT_DIM * 8 + 1024;
    int CH = (int)(remain / per_t);
    if (CH > T_STEPS) CH = T_STEPS;
    if (CH < 1) CH = 1;
    double* C3 = (double*)alloc((size_t)CH * B * OUT_DIM * 8);
    float* C   = (float*)alloc((size_t)CH * B * HID * 4);

    // ---- one-time prep ----
    cvt_w_i8<IN_DIM><<<((IN_DIM / 4) * HID + 255) / 256, 256, 0, stream>>>(wih, Bq1);
    cvt_w_i8<HID><<<((HID / 4) * HID + 255) / 256, 256, 0, stream>>>(whh, Bq2);
    cvt_who_i8<<<32, 256, 0, stream>>>(who, Bq3);
    bitpack_input<<<(B * (IN_DIM / 64)) / 4, 256, 0, stream>>>(inp, XbitsT);

    // ---- chunked time loop (CH=100 -> single chunk) ----
    for (int t0 = 0; t0 < T_STEPS; t0 += CH) {
        int L = T_STEPS - t0;
        if (L > CH) L = CH;
        int rows = L * B;            // multiple of 256
        int first = (t0 == 0) ? 1 : 0;

        // layer 1
        gemm_i8<IN_DIM><<<dim3(rows / 128, HID / 32), 256, 0, stream>>>(
            XbitsT, t0 * B, Bq1, C);
        lif_scan<<<(B * (HID / 64)) / 4, 256, 0, stream>>>(
            C, v1, S1T, t0 * B, L, first);

        // layer 2
        gemm_i8<HID><<<dim3(rows / 128, HID / 32), 256, 0, stream>>>(
            S1T, t0 * B, Bq2, C);
        lif_scan<<<(B * (HID / 64)) / 4, 256, 0, stream>>>(
            C, v2, S2T, t0 * B, L, first);

        // output layer
        gemm_out<<<rows / 256, 256, 0, stream>>>(S2T, t0 * B, Bq3, C3);
        lif_out<<<(B * OUT_DIM + 255) / 256, 256, 0, stream>>>(
            C3, vo, cnts, out, L, first);
    }
}

// Round 13
// 1259.996 us; speedup vs baseline: 1.6048x; 1.6048x over previous
//
#include <hip/hip_runtime.h>
#include <hip/hip_bf16.h>

// SNN: B=256, IN=1024, HID=2048, OUT=10, T=100, decay=0.9, thr=1.0, reset=0.
// Layer-pipelined: GEMM1(all t) -> LIF scan -> GEMM2(all t) -> scan -> GEMM3 -> scan.
// Hidden GEMMs: i8 Ozaki split, 4 digit planes of round(w*2^31) (exact split;
// i32 MFMA accumulation exact).
// Round-27 (vs r25/r26 REGRESSIONS, r24 best 811us):
//  - ROOT CAUSE of r25/r26 (both WRITE 2.5GB regardless of C pattern):
//    VGPR SPILLS, not RMW. launch_bounds(256,4) caps unified regs at 128;
//    r25/r26's mask ring r[4][4]=32 regs pushed demand to ~140 -> per-pair
//    spill/reload = 3.3GB scratch traffic, HBM-bound at 2.9TB/s.
//  - FIX: mask ring -> 1-pair lookahead r[2][4] (16 regs, like r24). Refills
//    load pair P+1's masks (w0+2/w0+3 = same indices as stages) right after
//    each expansion; consumed next pair (~1000cyc later, L2-covered).
//    Peak demand ~110 <= 128 -> no spills. vmcnt(8) still drains exactly
//    the 4 stages. VERIFY: WRITE_SIZE must return to ~205MB.
//  - KEPT (r26): 2x2 waves of 64rx16c (4 ds_read_b128/K-step, each feeds 4
//    MFMAs -> LDS-read demand halved vs r24's 76%-busy LDS pipe); epilogue
//    LDS exchange -> full 32-col row writes; results bit-identical
//    (absmax must stay exactly 0.01025391).
//  - KEPT (r24): 4-slot ring 4 blk/CU, pair-barrier discipline, gemm_out
//    dbuf, lif_scan 8-deep prefetch, LDS bitpack, i8-MFMA gemm_out, fp32 C
//    single chunk, cvt_who_i8, 8KB-region cvt_w_i8 swizzle.

#define B 256
#define IN_DIM 1024
#define HID 2048
#define OUT_DIM 10
#define T_STEPS 100
#define NCH 4
#define RT (T_STEPS * B)   // 25600 global rows

typedef unsigned long long ull;
typedef int v4i __attribute__((ext_vector_type(4)));

// ---- weight fp32 -> 4 signed base-256 digit planes of round(w*2^31),
// swizzled to MFMA fragment order: region per (nb32, wb) = 8192 B, fragment
// (c,ct) at (c*2+ct)*1024, byte lane*16+jj, lane=lk*16+li,
// n = nb32*32 + ct*16 + li, k = wb*64 + lk*16 + jj.
// One thread: 4 consecutive k (same n) -> coalesced W loads, dword stores. ----
template<int K>
__global__ __launch_bounds__(256) void cvt_w_i8(
    const float* __restrict__ W, signed char* __restrict__ Bq)
{
    constexpr int WPR = K / 64;
    size_t id = (size_t)blockIdx.x * 256 + threadIdx.x;
    if (id >= (size_t)(K / 4) * HID) return;
    int n  = (int)(id % HID);
    int kg = (int)(id / HID);
    int k0 = kg * 4;                                  // jj multiple of 4
    signed char dig[4][4];                            // [plane][i]
#pragma unroll
    for (int i = 0; i < 4; ++i) {
        double w = (double)W[(size_t)(k0 + i) * HID + n];
        long long V = __double2ll_rn(w * 2147483648.0);   // w * 2^31
#pragma unroll
        for (int c = 0; c < 3; ++c) {
            int r = (int)(signed char)(V & 0xFF);     // balanced digit [-128,127]
            dig[c][i] = (signed char)r;
            V = (V - r) >> 8;
        }
        dig[3][i] = (signed char)V;                   // |V| <= ~70
    }
    int wb = k0 >> 6, lk = (k0 >> 4) & 3, jj = k0 & 15;
    int nb32 = n >> 5, ct = (n >> 4) & 1, li = n & 15;
    int lane = lk * 16 + li;
    size_t base = ((size_t)nb32 * WPR + wb) * 8192 + (size_t)lane * 16 + jj;
#pragma unroll
    for (int c = 0; c < 4; ++c) {
        int pc = c * 2 + ct;                          // c=3 -> 6+ct
        unsigned pk = (unsigned)(unsigned char)dig[c][0]
                    | ((unsigned)(unsigned char)dig[c][1] << 8)
                    | ((unsigned)(unsigned char)dig[c][2] << 16)
                    | ((unsigned)(unsigned char)dig[c][3] << 24);
        *reinterpret_cast<unsigned*>(Bq + base + (size_t)pc * 1024) = pk;
    }
}

// ---- output weights fp32 -> 4 i8 digit planes (exact), MFMA fragment order.
// Region per w (64 k): 4 planes x 1024 B; byte = plane*1024 + lane*16 + jj.
// k = w*64 + lk*16 + jj, col = li (cols 10..15 zero-padded). ----
__global__ __launch_bounds__(256) void cvt_who_i8(
    const float* __restrict__ who, signed char* __restrict__ Bq3)
{
    int id = blockIdx.x * 256 + threadIdx.x;      // 32 w x 64 lane x 4 jj-groups
    if (id >= 32 * 64 * 4) return;
    int jg = id & 3;
    int lane = (id >> 2) & 63;
    int w = id >> 8;
    int li = lane & 15, lk = lane >> 4;
    signed char dig[4][4];
#pragma unroll
    for (int i = 0; i < 4; ++i) {
        int jj = jg * 4 + i;
        int k = w * 64 + lk * 16 + jj;
        double x = (li < OUT_DIM) ? (double)who[(size_t)k * OUT_DIM + li] : 0.0;
        long long V = __double2ll_rn(x * 2147483648.0);
#pragma unroll
        for (int c = 0; c < 3; ++c) {
            int r = (int)(signed char)(V & 0xFF);
            dig[c][i] = (signed char)r;
            V = (V - r) >> 8;
        }
        dig[3][i] = (signed char)V;
    }
    size_t base = (size_t)w * 4096 + (size_t)lane * 16 + jg * 4;
#pragma unroll
    for (int c = 0; c < 4; ++c) {
        unsigned pk = (unsigned)(unsigned char)dig[c][0]
                    | ((unsigned)(unsigned char)dig[c][1] << 8)
                    | ((unsigned)(unsigned char)dig[c][2] << 16)
                    | ((unsigned)(unsigned char)dig[c][3] << 24);
        *reinterpret_cast<unsigned*>(Bq3 + base + (size_t)c * 1024) = pk;
    }
}

// ---- bit-pack input spikes -> TRANSPOSED XbitsT[w][t*256+b] ----
// Coalesced: each wave stages [64 i][<=32 t] fp32 tiles into LDS (flat copy,
// pad-33 row stride -> conflict-free column reads), then ballots from LDS.
__global__ __launch_bounds__(256) void bitpack_input(
    const float* __restrict__ inp, ull* __restrict__ XbitsT)
{
    __shared__ float sb[4][64][33];   // 33.8 KB
    const int wv = threadIdx.x >> 6;
    const int lane = threadIdx.x & 63;
    const int g = blockIdx.x * 4 + wv;
    const int b = g >> 4;
    const int ig = g & 15;
    const float* __restrict__ src = inp + ((size_t)b * IN_DIM + ig * 64) * T_STEPS;
    ull* __restrict__ dst = XbitsT + (size_t)ig * RT + b;

#pragma unroll
    for (int tc = 0; tc < 4; ++tc) {
        const int t0 = tc * 32;
        if (tc < 3) {
#pragma unroll
            for (int f4 = 0; f4 < 32; ++f4) {
                int f = f4 * 64 + lane;
                int ii = f >> 5, tt = f & 31;
                sb[wv][ii][tt] = src[ii * T_STEPS + t0 + tt];
            }
        } else {
#pragma unroll
            for (int f4 = 0; f4 < 4; ++f4) {
                int f = f4 * 64 + lane;
                int ii = f >> 2, tt = f & 3;
                sb[wv][ii][tt] = src[ii * T_STEPS + t0 + tt];
            }
        }
        __syncthreads();
        const int len = (tc < 3) ? 32 : 4;
        for (int tt = 0; tt < len; ++tt) {
            float v = sb[wv][lane][tt];
            ull m = __ballot(v > 0.5f);
            if (lane == 0) dst[(size_t)(t0 + tt) * B] = m;
        }
        __syncthreads();
    }
}

// ---- i8 Ozaki bit-GEMM: 64x16 waves, 4-slot ring, 1-pair mask lookahead ----
// Block: 128 rows x 32 cols as 2x2 waves of 64 rows x 16 cols.
// Grid: x = rows/128, y = HID/32. row_base = t0*B (global row offset).
// Per K-step per wave: 4 ds_read_b128 (own col-half), each feeds 4 MFMAs.
// Per pair per wave: 4 stage + 8 mask loads; "s_waitcnt vmcnt(8); s_barrier".
// Mask ring r[2][4] (16 VGPR): refill with pair P+1 right after expansion.
// Epilogue: wc=1 -> LDS; wc=0 writes full 32-col rows (full 128B lines).
template<int K>
__global__ __launch_bounds__(256, 4) void gemm_i8(
    const ull* __restrict__ bitsT, int row_base,
    const signed char* __restrict__ Bq, float* __restrict__ C)
{
    constexpr int WPR = K / 64;          // 16 (L1) / 32 (L2)
    constexpr int NP  = WPR / 2;         // pairs: 8 / 16  (even)
    __shared__ __align__(16) signed char blds[4][8192];   // 32 KB -> 4 blk/CU

    const int tid = threadIdx.x;
    const int lane = tid & 63;
    const int wv = __builtin_amdgcn_readfirstlane(tid >> 6);
    const int wr = wv >> 1;                               // row half 0/1
    const int wc = wv & 1;                                // col half 0/1
    const int row0 = blockIdx.x * 128;                    // local row base
    const int c0 = blockIdx.y * 32;
    const int li = lane & 15;
    const int lk = lane >> 4;
    const int sh = lk * 16;
    const int r0l = wr * 64;

    const signed char* __restrict__ bsrc = Bq + (size_t)blockIdx.y * WPR * 8192;
    // lane li (replicated over lk) holds mask of row row0 + wr*64 + g*16 + li
    const ull* __restrict__ mp = bitsT + (row_base + row0 + r0l + li);

    // stage B(w) into ring slot: 8 segments of 1 KB, 2 per wave (async to LDS)
    auto stage_b = [&](int w, int slot) {
        const signed char* src = bsrc + (size_t)w * 8192 + lane * 16;
        signed char* db = &blds[0][0] + slot * 8192;
        __builtin_amdgcn_global_load_lds(
            (const __attribute__((address_space(1))) unsigned int*)(src + wv * 1024),
            (__attribute__((address_space(3))) unsigned int*)(db + wv * 1024), 16, 0, 0);
        __builtin_amdgcn_global_load_lds(
            (const __attribute__((address_space(1))) unsigned int*)(src + (wv + 4) * 1024),
            (__attribute__((address_space(3))) unsigned int*)(db + (wv + 4) * 1024), 16, 0, 0);
    };

    // prologue: stage pair 0 (w=0,1 -> slots 0,1); masks for pair 0 only
    stage_b(0, 0);
    stage_b(1, 1);
    ull r[2][4];                         // [step-in-pair][row-group] = 16 VGPR
#pragma unroll
    for (int g = 0; g < 4; ++g) {
        r[0][g] = mp[(size_t)0 * RT + g * 16];
        r[1][g] = mp[(size_t)1 * RT + g * 16];
    }
    __syncthreads();   // full drain once (prologue)

    v4i acc[4][NCH];                     // [row-group][plane] = 64 VGPR
#pragma unroll
    for (int g = 0; g < 4; ++g)
#pragma unroll
        for (int c = 0; c < NCH; ++c) acc[g][c] = (v4i){0, 0, 0, 0};

    // Ring: pair P (parity q) reads slots {2q,2q+1}; stages w=2P+2,2P+3 into
    // {2-2q,3-2q} (consumed at P-1; the P-1 -> P barrier protects them).
    // Mask ring r[st][g]: expand pair P's step st, then refill with pair
    // P+1's step st (w0+2 / w0+3 - same indices as the stages). Consumed
    // next pair; compiler dep-waitcnt covers arrival. Tail wraps dummy-valid.
#pragma unroll 1
    for (int p2 = 0; p2 < NP; p2 += 2) {  // 2 pairs per outer iter (idx const)
#pragma unroll
        for (int pp = 0; pp < 2; ++pp) {
            const int w0 = (p2 + pp) * 2;           // first w of pair
            const int q  = pp;                      // pair parity (p2 even)
            const int s0 = 2 * q, s1 = 2 * q + 1;   // consume slots
            const int tA = 2 - 2 * q, tB = 3 - 2 * q;   // stage slots

            // stage NEXT pair FIRST
            int wn0 = w0 + 2; if (wn0 >= WPR) wn0 -= WPR;   // tail: dummy-valid
            int wn1 = w0 + 3; if (wn1 >= WPR) wn1 -= WPR;
            stage_b(wn0, tA);
            stage_b(wn1, tB);

            // ---- K-step A (w0), slot s0 ----
            {
                v4i a[4];
#pragma unroll
                for (int g = 0; g < 4; ++g) {
                    unsigned s = (unsigned)(r[0][g] >> sh) & 0xFFFFu;
#pragma unroll
                    for (int d = 0; d < 4; ++d)
                        a[g][d] = (int)((((s >> (4 * d)) & 0xFu) * 0x00204081u) & 0x01010101u);
                }
#pragma unroll
                for (int g = 0; g < 4; ++g)          // refill: pair P+1 step A
                    r[0][g] = mp[(size_t)wn0 * RT + g * 16];
                const signed char* bb = &blds[0][0] + s0 * 8192 + lane * 16;
                __builtin_amdgcn_s_setprio(1);
#pragma unroll
                for (int c = 0; c < NCH; ++c) {
                    v4i b = *(const v4i*)(bb + (c * 2 + wc) * 1024);
#pragma unroll
                    for (int g = 0; g < 4; ++g)
                        acc[g][c] = __builtin_amdgcn_mfma_i32_16x16x64_i8(a[g], b, acc[g][c], 0, 0, 0);
                }
                __builtin_amdgcn_s_setprio(0);
            }
            // ---- K-step B (w0+1), slot s1 ----
            {
                v4i a[4];
#pragma unroll
                for (int g = 0; g < 4; ++g) {
                    unsigned s = (unsigned)(r[1][g] >> sh) & 0xFFFFu;
#pragma unroll
                    for (int d = 0; d < 4; ++d)
                        a[g][d] = (int)((((s >> (4 * d)) & 0xFu) * 0x00204081u) & 0x01010101u);
                }
#pragma unroll
                for (int g = 0; g < 4; ++g)          // refill: pair P+1 step B
                    r[1][g] = mp[(size_t)wn1 * RT + g * 16];
                const signed char* bb = &blds[0][0] + s1 * 8192 + lane * 16;
                __builtin_amdgcn_s_setprio(1);
#pragma unroll
                for (int c = 0; c < NCH; ++c) {
                    v4i b = *(const v4i*)(bb + (c * 2 + wc) * 1024);
#pragma unroll
                    for (int g = 0; g < 4; ++g)
                        acc[g][c] = __builtin_amdgcn_mfma_i32_16x16x64_i8(a[g], b, acc[g][c], 0, 0, 0);
                }
                __builtin_amdgcn_s_setprio(0);
            }

            // drain this pair's 4 stages; the 8 mask refills stay in flight
            __asm__ __volatile__("s_waitcnt vmcnt(8)\n\ts_barrier" ::: "memory");
        }
    }

    // ---- epilogue: exact recombination + cross-wave col-half exchange ----
    // V = (((S3<<8)+S2)<<8+S1)<<8+S0; |V| < 2^43. fp32 conversion BEFORE
    // exchange (bit-identical to direct store). wc=1 -> LDS (8KB of dead
    // blds); wc=0 writes full 32-col rows = full 128B lines from one wave.
    float fv[4][4];
#pragma unroll
    for (int g = 0; g < 4; ++g) {
#pragma unroll
        for (int rr = 0; rr < 4; ++rr) {
            long long V = (long long)acc[g][3][rr];
            V = (V << 8) + (long long)acc[g][2][rr];
            V = (V << 8) + (long long)acc[g][1][rr];
            V = (V << 8) + (long long)acc[g][0][rr];
            fv[g][rr] = (float)((double)V * 0x1p-31);
        }
    }
    __syncthreads();   // drains tail stage loads before blds reuse
    float* __restrict__ xch = (float*)&blds[0][0];   // [2 wr][16 g*4+rr][64 lane]
    if (wc == 1) {
#pragma unroll
        for (int g = 0; g < 4; ++g)
#pragma unroll
            for (int rr = 0; rr < 4; ++rr)
                xch[(wr * 16 + g * 4 + rr) * 64 + lane] = fv[g][rr];
    }
    __syncthreads();
    if (wc == 0) {
#pragma unroll
        for (int g = 0; g < 4; ++g) {
#pragma unroll
            for (int rr = 0; rr < 4; ++rr) {
                float hi = xch[(wr * 16 + g * 4 + rr) * 64 + lane];
                size_t base = (size_t)(row0 + r0l + g * 16 + lk * 4 + rr) * HID + c0;
                C[base + li] = fv[g][rr];
                C[base + 16 + li] = hi;
            }
        }
    }
}

// ---- output bit-GEMM via i8 MFMA: 16-col tile (10 used), 4 exact planes ----
// Block: 256 rows, 4 waves (wave = 64 rows x 16 cols). Grid: rows/256.
// Latency-exposed (0.4 blk/CU) -> masks+B double-buffered one w ahead.
__global__ __launch_bounds__(256) void gemm_out(
    const ull* __restrict__ bitsT, int row_base,
    const signed char* __restrict__ Bq3, double* __restrict__ C3)
{
    const int lane = threadIdx.x & 63;
    const int wv = threadIdx.x >> 6;
    const int li = lane & 15;
    const int lk = lane >> 4;
    const int sh = lk * 16;
    const int row0 = blockIdx.x * 256 + wv * 64;
    const ull* __restrict__ mp = bitsT + (row_base + row0 + li);

    v4i acc[4][NCH];   // [row-group][plane]
#pragma unroll
    for (int g = 0; g < 4; ++g)
#pragma unroll
        for (int c = 0; c < NCH; ++c) acc[g][c] = (v4i){0, 0, 0, 0};

    ull m[2][4];
    v4i b[2][NCH];
    // prologue: load w=0 into buf 0
#pragma unroll
    for (int g = 0; g < 4; ++g) m[0][g] = mp[(size_t)0 * RT + g * 16];
    {
        const v4i* __restrict__ bp = (const v4i*)(Bq3 + (size_t)lane * 16);
#pragma unroll
        for (int c = 0; c < NCH; ++c) b[0][c] = bp[c * 64];
    }

#pragma unroll 2
    for (int w = 0; w < 32; ++w) {
        const int cur = w & 1, nxt = cur ^ 1;
        if (w < 31) {   // prefetch w+1 into nxt
#pragma unroll
            for (int g = 0; g < 4; ++g) m[nxt][g] = mp[(size_t)(w + 1) * RT + g * 16];
            const v4i* __restrict__ bp =
                (const v4i*)(Bq3 + (size_t)(w + 1) * 4096 + (size_t)lane * 16);
#pragma unroll
            for (int c = 0; c < NCH; ++c) b[nxt][c] = bp[c * 64];
        }
#pragma unroll
        for (int g = 0; g < 4; ++g) {
            unsigned s = (unsigned)(m[cur][g] >> sh) & 0xFFFFu;
            v4i a;
#pragma unroll
            for (int d = 0; d < 4; ++d)
                a[d] = (int)((((s >> (4 * d)) & 0xFu) * 0x00204081u) & 0x01010101u);
#pragma unroll
            for (int c = 0; c < NCH; ++c)
                acc[g][c] = __builtin_amdgcn_mfma_i32_16x16x64_i8(a, b[cur][c], acc[g][c], 0, 0, 0);
        }
    }

    if (li < OUT_DIM) {
#pragma unroll
        for (int g = 0; g < 4; ++g) {
#pragma unroll
            for (int rr = 0; rr < 4; ++rr) {
                long long V = (long long)acc[g][3][rr];
                V = (V << 8) + (long long)acc[g][2][rr];
                V = (V << 8) + (long long)acc[g][1][rr];
                V = (V << 8) + (long long)acc[g][0][rr];
                C3[(size_t)(row0 + g * 16 + lk * 4 + rr) * OUT_DIM + li] =
                    (double)V * 0x1p-31;
            }
        }
    }
}

// ---- LIF scan for a hidden layer; 8-deep load prefetch ----
__global__ __launch_bounds__(256) void lif_scan(
    const float* __restrict__ C, double* __restrict__ vstate,
    ull* __restrict__ SbitsT, int row_base, int Tl, int first)
{
    int g = blockIdx.x * 4 + (threadIdx.x >> 6);
    int lane = threadIdx.x & 63;
    int b = g >> 5;
    int ng = g & 31;
    int n = ng * 64 + lane;
    const float* __restrict__ Cp = C + (size_t)b * HID + n;
    ull* __restrict__ Sp = SbitsT + (size_t)ng * RT + row_base + b;
    double v = first ? 0.0 : vstate[(size_t)b * HID + n];
    int tl = 0;
    for (; tl + 8 <= Tl; tl += 8) {
        float cc[8];
#pragma unroll
        for (int i = 0; i < 8; ++i)
            cc[i] = Cp[(size_t)(tl + i) * (B * HID)];
#pragma unroll
        for (int i = 0; i < 8; ++i) {
            v = v * 0.9 + (double)cc[i];
            bool s = (v >= 1.0);
            if (s) v = 0.0;
            ull mask = __ballot(s);
            if (lane == 0) Sp[(size_t)(tl + i) * B] = mask;
        }
    }
    for (; tl < Tl; ++tl) {
        double c = (double)Cp[(size_t)tl * (B * HID)];
        v = v * 0.9 + c;
        bool s = (v >= 1.0);
        if (s) v = 0.0;
        ull mask = __ballot(s);
        if (lane == 0) Sp[(size_t)tl * B] = mask;
    }
    vstate[(size_t)b * HID + n] = v;
}

// ---- output LIF scan + rate accumulation; 4-deep prefetch ----
__global__ __launch_bounds__(256) void lif_out(
    const double* __restrict__ C3, double* __restrict__ vstate,
    int* __restrict__ cnt_state, float* __restrict__ out, int Tl, int first)
{
    int tid = blockIdx.x * 256 + threadIdx.x;
    if (tid >= B * OUT_DIM) return;
    int b = tid / OUT_DIM, o = tid % OUT_DIM;
    const double* __restrict__ Cp = C3 + (size_t)b * OUT_DIM + o;
    double v = first ? 0.0 : vstate[tid];
    int cnt = first ? 0 : cnt_state[tid];
    int tl = 0;
    for (; tl + 4 <= Tl; tl += 4) {
        double c0 = Cp[(size_t)(tl + 0) * (B * OUT_DIM)];
        double c1 = Cp[(size_t)(tl + 1) * (B * OUT_DIM)];
        double c2 = Cp[(size_t)(tl + 2) * (B * OUT_DIM)];
        double c3 = Cp[(size_t)(tl + 3) * (B * OUT_DIM)];
#pragma unroll
        for (int i = 0; i < 4; ++i) {
            double cc = (i == 0) ? c0 : (i == 1) ? c1 : (i == 2) ? c2 : c3;
            v = v * 0.9 + cc;
            if (v >= 1.0) { cnt++; v = 0.0; }
        }
    }
    for (; tl < Tl; ++tl) {
        double c = Cp[(size_t)tl * (B * OUT_DIM)];
        v = v * 0.9 + c;
        if (v >= 1.0) { cnt++; v = 0.0; }
    }
    vstate[tid] = v;
    cnt_state[tid] = cnt;
    out[tid] = (float)((double)cnt / (double)T_STEPS);
}

extern "C" void kernel_launch(void* const* d_in, const int* in_sizes, int n_in,
                              void* d_out, int out_size, void* d_ws, size_t ws_size,
                              hipStream_t stream) {
    const float* inp = (const float*)d_in[0];   // [256,1024,100]
    const float* wih = (const float*)d_in[1];   // [1024,2048]
    const float* whh = (const float*)d_in[2];   // [1,2048,2048]
    const float* who = (const float*)d_in[3];   // [2048,10]
    float* out = (float*)d_out;                 // [256,10]

    // ---- workspace layout ----
    unsigned char* p = (unsigned char*)d_ws;
    auto alloc = [&](size_t sz) -> void* {
        void* r = (void*)p;
        p += (sz + 255) & ~(size_t)255;
        return r;
    };
    signed char* Bq1 = (signed char*)alloc((size_t)NCH * HID * IN_DIM + 4096); // 8.4 MB
    signed char* Bq2 = (signed char*)alloc((size_t)NCH * HID * HID + 4096);    // 16.8 MB
    signed char* Bq3 = (signed char*)alloc((size_t)32 * 4096 + 4096);          // 132 KB
    ull* XbitsT = (ull*)alloc((size_t)16 * RT * 8);        // 3.3 MB
    ull* S1T    = (ull*)alloc((size_t)32 * RT * 8);        // 6.6 MB
    ull* S2T    = (ull*)alloc((size_t)32 * RT * 8);        // 6.6 MB
    double* v1 = (double*)alloc((size_t)B * HID * 8);
    double* v2 = (double*)alloc((size_t)B * HID * 8);
    double* vo = (double*)alloc((size_t)B * OUT_DIM * 8);
    int* cnts  = (int*)alloc((size_t)B * OUT_DIM * 4);

    size_t used = (size_t)(p - (unsigned char*)d_ws);
    size_t remain = (ws_size > used) ? (ws_size - used) : 0;
    size_t per_t = (size_t)B * HID * 4 + (size_t)B * OUT_DIM * 8 + 1024;
    int CH = (int)(remain / per_t);
    if (CH > T_STEPS) CH = T_STEPS;
    if (CH < 1) CH = 1;
    double* C3 = (double*)alloc((size_t)CH * B * OUT_DIM * 8);
    float* C   = (float*)alloc((size_t)CH * B * HID * 4);

    // ---- one-time prep ----
    cvt_w_i8<IN_DIM><<<((IN_DIM / 4) * HID + 255) / 256, 256, 0, stream>>>(wih, Bq1);
    cvt_w_i8<HID><<<((HID / 4) * HID + 255) / 256, 256, 0, stream>>>(whh, Bq2);
    cvt_who_i8<<<32, 256, 0, stream>>>(who, Bq3);
    bitpack_input<<<(B * (IN_DIM / 64)) / 4, 256, 0, stream>>>(inp, XbitsT);

    // ---- chunked time loop (CH=100 -> single chunk) ----
    for (int t0 = 0; t0 < T_STEPS; t0 += CH) {
        int L = T_STEPS - t0;
        if (L > CH) L = CH;
        int rows = L * B;            // multiple of 256
        int first = (t0 == 0) ? 1 : 0;

        // layer 1
        gemm_i8<IN_DIM><<<dim3(rows / 128, HID / 32), 256, 0, stream>>>(
            XbitsT, t0 * B, Bq1, C);
        lif_scan<<<(B * (HID / 64)) / 4, 256, 0, stream>>>(
            C, v1, S1T, t0 * B, L, first);

        // layer 2
        gemm_i8<HID><<<dim3(rows / 128, HID / 32), 256, 0, stream>>>(
            S1T, t0 * B, Bq2, C);
        lif_scan<<<(B * (HID / 64)) / 4, 256, 0, stream>>>(
            C, v2, S2T, t0 * B, L, first);

        // output layer
        gemm_out<<<rows / 256, 256, 0, stream>>>(S2T, t0 * B, Bq3, C3);
        lif_out<<<(B * OUT_DIM + 255) / 256, 256, 0, stream>>>(
            C3, vo, cnts, out, L, first);
    }
}

// Round 14
// 982.488 us; speedup vs baseline: 2.0580x; 1.2825x over previous
//
#include <hip/hip_runtime.h>
#include <hip/hip_bf16.h>

// SNN: B=256, IN=1024, HID=2048, OUT=10, T=100, decay=0.9, thr=1.0, reset=0.
// Layer-pipelined: GEMM1(all t) -> LIF scan -> GEMM2(all t) -> scan -> GEMM3 -> scan.
// Hidden GEMMs: i8 Ozaki split, 4 digit planes of round(w*2^31) (exact split;
// i32 MFMA accumulation exact).
// Round-28 (vs r27; r24=811us is the proven fallback):
//  - gemm_i8: ONE change vs r27: __launch_bounds__(256,4) -> (256,3).
//    r27 still spilled (WRITE 695MB vs 205 expected; MfmaUtil 28) - the
//    64x16-wave loop's true register demand is ~140-150, over the 128 cap.
//    Cap 170 (3 waves/SIMD) gives the allocator slack -> no spills. The
//    re-tile's purpose survives at 3 blocks/CU: LDS-read demand per pair
//    1152 cyc/CU (vs r17's 2304 at same occupancy) -> matrix pipe binding.
//    FAILURE CRITERION: WRITE_SIZE > 300MB -> revert to r24 permanently.
//    Results bit-identical -> absmax must stay exactly 0.01025391.
//  - All else r27-verbatim: 2x2 waves of 64rx16c, 4-slot ring, pair-barrier
//    vmcnt(8), 1-pair mask lookahead r[2][4], epilogue LDS exchange ->
//    full 32-col row writes, gemm_out dbuf, lif_scan 8-deep prefetch,
//    LDS bitpack, i8-MFMA gemm_out, fp32 C single chunk, cvt_who_i8,
//    8KB-region cvt_w_i8 swizzle.

#define B 256
#define IN_DIM 1024
#define HID 2048
#define OUT_DIM 10
#define T_STEPS 100
#define NCH 4
#define RT (T_STEPS * B)   // 25600 global rows

typedef unsigned long long ull;
typedef int v4i __attribute__((ext_vector_type(4)));

// ---- weight fp32 -> 4 signed base-256 digit planes of round(w*2^31),
// swizzled to MFMA fragment order: region per (nb32, wb) = 8192 B, fragment
// (c,ct) at (c*2+ct)*1024, byte lane*16+jj, lane=lk*16+li,
// n = nb32*32 + ct*16 + li, k = wb*64 + lk*16 + jj.
// One thread: 4 consecutive k (same n) -> coalesced W loads, dword stores. ----
template<int K>
__global__ __launch_bounds__(256) void cvt_w_i8(
    const float* __restrict__ W, signed char* __restrict__ Bq)
{
    constexpr int WPR = K / 64;
    size_t id = (size_t)blockIdx.x * 256 + threadIdx.x;
    if (id >= (size_t)(K / 4) * HID) return;
    int n  = (int)(id % HID);
    int kg = (int)(id / HID);
    int k0 = kg * 4;                                  // jj multiple of 4
    signed char dig[4][4];                            // [plane][i]
#pragma unroll
    for (int i = 0; i < 4; ++i) {
        double w = (double)W[(size_t)(k0 + i) * HID + n];
        long long V = __double2ll_rn(w * 2147483648.0);   // w * 2^31
#pragma unroll
        for (int c = 0; c < 3; ++c) {
            int r = (int)(signed char)(V & 0xFF);     // balanced digit [-128,127]
            dig[c][i] = (signed char)r;
            V = (V - r) >> 8;
        }
        dig[3][i] = (signed char)V;                   // |V| <= ~70
    }
    int wb = k0 >> 6, lk = (k0 >> 4) & 3, jj = k0 & 15;
    int nb32 = n >> 5, ct = (n >> 4) & 1, li = n & 15;
    int lane = lk * 16 + li;
    size_t base = ((size_t)nb32 * WPR + wb) * 8192 + (size_t)lane * 16 + jj;
#pragma unroll
    for (int c = 0; c < 4; ++c) {
        int pc = c * 2 + ct;                          // c=3 -> 6+ct
        unsigned pk = (unsigned)(unsigned char)dig[c][0]
                    | ((unsigned)(unsigned char)dig[c][1] << 8)
                    | ((unsigned)(unsigned char)dig[c][2] << 16)
                    | ((unsigned)(unsigned char)dig[c][3] << 24);
        *reinterpret_cast<unsigned*>(Bq + base + (size_t)pc * 1024) = pk;
    }
}

// ---- output weights fp32 -> 4 i8 digit planes (exact), MFMA fragment order.
// Region per w (64 k): 4 planes x 1024 B; byte = plane*1024 + lane*16 + jj.
// k = w*64 + lk*16 + jj, col = li (cols 10..15 zero-padded). ----
__global__ __launch_bounds__(256) void cvt_who_i8(
    const float* __restrict__ who, signed char* __restrict__ Bq3)
{
    int id = blockIdx.x * 256 + threadIdx.x;      // 32 w x 64 lane x 4 jj-groups
    if (id >= 32 * 64 * 4) return;
    int jg = id & 3;
    int lane = (id >> 2) & 63;
    int w = id >> 8;
    int li = lane & 15, lk = lane >> 4;
    signed char dig[4][4];
#pragma unroll
    for (int i = 0; i < 4; ++i) {
        int jj = jg * 4 + i;
        int k = w * 64 + lk * 16 + jj;
        double x = (li < OUT_DIM) ? (double)who[(size_t)k * OUT_DIM + li] : 0.0;
        long long V = __double2ll_rn(x * 2147483648.0);
#pragma unroll
        for (int c = 0; c < 3; ++c) {
            int r = (int)(signed char)(V & 0xFF);
            dig[c][i] = (signed char)r;
            V = (V - r) >> 8;
        }
        dig[3][i] = (signed char)V;
    }
    size_t base = (size_t)w * 4096 + (size_t)lane * 16 + jg * 4;
#pragma unroll
    for (int c = 0; c < 4; ++c) {
        unsigned pk = (unsigned)(unsigned char)dig[c][0]
                    | ((unsigned)(unsigned char)dig[c][1] << 8)
                    | ((unsigned)(unsigned char)dig[c][2] << 16)
                    | ((unsigned)(unsigned char)dig[c][3] << 24);
        *reinterpret_cast<unsigned*>(Bq3 + base + (size_t)c * 1024) = pk;
    }
}

// ---- bit-pack input spikes -> TRANSPOSED XbitsT[w][t*256+b] ----
// Coalesced: each wave stages [64 i][<=32 t] fp32 tiles into LDS (flat copy,
// pad-33 row stride -> conflict-free column reads), then ballots from LDS.
__global__ __launch_bounds__(256) void bitpack_input(
    const float* __restrict__ inp, ull* __restrict__ XbitsT)
{
    __shared__ float sb[4][64][33];   // 33.8 KB
    const int wv = threadIdx.x >> 6;
    const int lane = threadIdx.x & 63;
    const int g = blockIdx.x * 4 + wv;
    const int b = g >> 4;
    const int ig = g & 15;
    const float* __restrict__ src = inp + ((size_t)b * IN_DIM + ig * 64) * T_STEPS;
    ull* __restrict__ dst = XbitsT + (size_t)ig * RT + b;

#pragma unroll
    for (int tc = 0; tc < 4; ++tc) {
        const int t0 = tc * 32;
        if (tc < 3) {
#pragma unroll
            for (int f4 = 0; f4 < 32; ++f4) {
                int f = f4 * 64 + lane;
                int ii = f >> 5, tt = f & 31;
                sb[wv][ii][tt] = src[ii * T_STEPS + t0 + tt];
            }
        } else {
#pragma unroll
            for (int f4 = 0; f4 < 4; ++f4) {
                int f = f4 * 64 + lane;
                int ii = f >> 2, tt = f & 3;
                sb[wv][ii][tt] = src[ii * T_STEPS + t0 + tt];
            }
        }
        __syncthreads();
        const int len = (tc < 3) ? 32 : 4;
        for (int tt = 0; tt < len; ++tt) {
            float v = sb[wv][lane][tt];
            ull m = __ballot(v > 0.5f);
            if (lane == 0) dst[(size_t)(t0 + tt) * B] = m;
        }
        __syncthreads();
    }
}

// ---- i8 Ozaki bit-GEMM: 64x16 waves, 4-slot ring, cap-170 regs ----
// Block: 128 rows x 32 cols as 2x2 waves of 64 rows x 16 cols.
// Grid: x = rows/128, y = HID/32. row_base = t0*B (global row offset).
// Per K-step per wave: 4 ds_read_b128 (own col-half), each feeds 4 MFMAs.
// Per pair per wave: 4 stage + 8 mask loads; "s_waitcnt vmcnt(8); s_barrier".
// Mask ring r[2][4] (16 VGPR): refill with pair P+1 right after expansion.
// Epilogue: wc=1 -> LDS; wc=0 writes full 32-col rows (full 128B lines).
template<int K>
__global__ __launch_bounds__(256, 3) void gemm_i8(
    const ull* __restrict__ bitsT, int row_base,
    const signed char* __restrict__ Bq, float* __restrict__ C)
{
    constexpr int WPR = K / 64;          // 16 (L1) / 32 (L2)
    constexpr int NP  = WPR / 2;         // pairs: 8 / 16  (even)
    __shared__ __align__(16) signed char blds[4][8192];   // 32 KB

    const int tid = threadIdx.x;
    const int lane = tid & 63;
    const int wv = __builtin_amdgcn_readfirstlane(tid >> 6);
    const int wr = wv >> 1;                               // row half 0/1
    const int wc = wv & 1;                                // col half 0/1
    const int row0 = blockIdx.x * 128;                    // local row base
    const int c0 = blockIdx.y * 32;
    const int li = lane & 15;
    const int lk = lane >> 4;
    const int sh = lk * 16;
    const int r0l = wr * 64;

    const signed char* __restrict__ bsrc = Bq + (size_t)blockIdx.y * WPR * 8192;
    // lane li (replicated over lk) holds mask of row row0 + wr*64 + g*16 + li
    const ull* __restrict__ mp = bitsT + (row_base + row0 + r0l + li);

    // stage B(w) into ring slot: 8 segments of 1 KB, 2 per wave (async to LDS)
    auto stage_b = [&](int w, int slot) {
        const signed char* src = bsrc + (size_t)w * 8192 + lane * 16;
        signed char* db = &blds[0][0] + slot * 8192;
        __builtin_amdgcn_global_load_lds(
            (const __attribute__((address_space(1))) unsigned int*)(src + wv * 1024),
            (__attribute__((address_space(3))) unsigned int*)(db + wv * 1024), 16, 0, 0);
        __builtin_amdgcn_global_load_lds(
            (const __attribute__((address_space(1))) unsigned int*)(src + (wv + 4) * 1024),
            (__attribute__((address_space(3))) unsigned int*)(db + (wv + 4) * 1024), 16, 0, 0);
    };

    // prologue: stage pair 0 (w=0,1 -> slots 0,1); masks for pair 0 only
    stage_b(0, 0);
    stage_b(1, 1);
    ull r[2][4];                         // [step-in-pair][row-group] = 16 VGPR
#pragma unroll
    for (int g = 0; g < 4; ++g) {
        r[0][g] = mp[(size_t)0 * RT + g * 16];
        r[1][g] = mp[(size_t)1 * RT + g * 16];
    }
    __syncthreads();   // full drain once (prologue)

    v4i acc[4][NCH];                     // [row-group][plane] = 64 VGPR
#pragma unroll
    for (int g = 0; g < 4; ++g)
#pragma unroll
        for (int c = 0; c < NCH; ++c) acc[g][c] = (v4i){0, 0, 0, 0};

    // Ring: pair P (parity q) reads slots {2q,2q+1}; stages w=2P+2,2P+3 into
    // {2-2q,3-2q} (consumed at P-1; the P-1 -> P barrier protects them).
    // Mask ring r[st][g]: expand pair P's step st, then refill with pair
    // P+1's step st (w0+2 / w0+3 - same indices as the stages). Consumed
    // next pair; compiler dep-waitcnt covers arrival. Tail wraps dummy-valid.
#pragma unroll 1
    for (int p2 = 0; p2 < NP; p2 += 2) {  // 2 pairs per outer iter (idx const)
#pragma unroll
        for (int pp = 0; pp < 2; ++pp) {
            const int w0 = (p2 + pp) * 2;           // first w of pair
            const int q  = pp;                      // pair parity (p2 even)
            const int s0 = 2 * q, s1 = 2 * q + 1;   // consume slots
            const int tA = 2 - 2 * q, tB = 3 - 2 * q;   // stage slots

            // stage NEXT pair FIRST
            int wn0 = w0 + 2; if (wn0 >= WPR) wn0 -= WPR;   // tail: dummy-valid
            int wn1 = w0 + 3; if (wn1 >= WPR) wn1 -= WPR;
            stage_b(wn0, tA);
            stage_b(wn1, tB);

            // ---- K-step A (w0), slot s0 ----
            {
                v4i a[4];
#pragma unroll
                for (int g = 0; g < 4; ++g) {
                    unsigned s = (unsigned)(r[0][g] >> sh) & 0xFFFFu;
#pragma unroll
                    for (int d = 0; d < 4; ++d)
                        a[g][d] = (int)((((s >> (4 * d)) & 0xFu) * 0x00204081u) & 0x01010101u);
                }
#pragma unroll
                for (int g = 0; g < 4; ++g)          // refill: pair P+1 step A
                    r[0][g] = mp[(size_t)wn0 * RT + g * 16];
                const signed char* bb = &blds[0][0] + s0 * 8192 + lane * 16;
                __builtin_amdgcn_s_setprio(1);
#pragma unroll
                for (int c = 0; c < NCH; ++c) {
                    v4i b = *(const v4i*)(bb + (c * 2 + wc) * 1024);
#pragma unroll
                    for (int g = 0; g < 4; ++g)
                        acc[g][c] = __builtin_amdgcn_mfma_i32_16x16x64_i8(a[g], b, acc[g][c], 0, 0, 0);
                }
                __builtin_amdgcn_s_setprio(0);
            }
            // ---- K-step B (w0+1), slot s1 ----
            {
                v4i a[4];
#pragma unroll
                for (int g = 0; g < 4; ++g) {
                    unsigned s = (unsigned)(r[1][g] >> sh) & 0xFFFFu;
#pragma unroll
                    for (int d = 0; d < 4; ++d)
                        a[g][d] = (int)((((s >> (4 * d)) & 0xFu) * 0x00204081u) & 0x01010101u);
                }
#pragma unroll
                for (int g = 0; g < 4; ++g)          // refill: pair P+1 step B
                    r[1][g] = mp[(size_t)wn1 * RT + g * 16];
                const signed char* bb = &blds[0][0] + s1 * 8192 + lane * 16;
                __builtin_amdgcn_s_setprio(1);
#pragma unroll
                for (int c = 0; c < NCH; ++c) {
                    v4i b = *(const v4i*)(bb + (c * 2 + wc) * 1024);
#pragma unroll
                    for (int g = 0; g < 4; ++g)
                        acc[g][c] = __builtin_amdgcn_mfma_i32_16x16x64_i8(a[g], b, acc[g][c], 0, 0, 0);
                }
                __builtin_amdgcn_s_setprio(0);
            }

            // drain this pair's 4 stages; the 8 mask refills stay in flight
            __asm__ __volatile__("s_waitcnt vmcnt(8)\n\ts_barrier" ::: "memory");
        }
    }

    // ---- epilogue: exact recombination + cross-wave col-half exchange ----
    // V = (((S3<<8)+S2)<<8+S1)<<8+S0; |V| < 2^43. fp32 conversion BEFORE
    // exchange (bit-identical to direct store). wc=1 -> LDS (8KB of dead
    // blds); wc=0 writes full 32-col rows = full 128B lines from one wave.
    float fv[4][4];
#pragma unroll
    for (int g = 0; g < 4; ++g) {
#pragma unroll
        for (int rr = 0; rr < 4; ++rr) {
            long long V = (long long)acc[g][3][rr];
            V = (V << 8) + (long long)acc[g][2][rr];
            V = (V << 8) + (long long)acc[g][1][rr];
            V = (V << 8) + (long long)acc[g][0][rr];
            fv[g][rr] = (float)((double)V * 0x1p-31);
        }
    }
    __syncthreads();   // drains tail stage loads before blds reuse
    float* __restrict__ xch = (float*)&blds[0][0];   // [2 wr][16 g*4+rr][64 lane]
    if (wc == 1) {
#pragma unroll
        for (int g = 0; g < 4; ++g)
#pragma unroll
            for (int rr = 0; rr < 4; ++rr)
                xch[(wr * 16 + g * 4 + rr) * 64 + lane] = fv[g][rr];
    }
    __syncthreads();
    if (wc == 0) {
#pragma unroll
        for (int g = 0; g < 4; ++g) {
#pragma unroll
            for (int rr = 0; rr < 4; ++rr) {
                float hi = xch[(wr * 16 + g * 4 + rr) * 64 + lane];
                size_t base = (size_t)(row0 + r0l + g * 16 + lk * 4 + rr) * HID + c0;
                C[base + li] = fv[g][rr];
                C[base + 16 + li] = hi;
            }
        }
    }
}

// ---- output bit-GEMM via i8 MFMA: 16-col tile (10 used), 4 exact planes ----
// Block: 256 rows, 4 waves (wave = 64 rows x 16 cols). Grid: rows/256.
// Latency-exposed (0.4 blk/CU) -> masks+B double-buffered one w ahead.
__global__ __launch_bounds__(256) void gemm_out(
    const ull* __restrict__ bitsT, int row_base,
    const signed char* __restrict__ Bq3, double* __restrict__ C3)
{
    const int lane = threadIdx.x & 63;
    const int wv = threadIdx.x >> 6;
    const int li = lane & 15;
    const int lk = lane >> 4;
    const int sh = lk * 16;
    const int row0 = blockIdx.x * 256 + wv * 64;
    const ull* __restrict__ mp = bitsT + (row_base + row0 + li);

    v4i acc[4][NCH];   // [row-group][plane]
#pragma unroll
    for (int g = 0; g < 4; ++g)
#pragma unroll
        for (int c = 0; c < NCH; ++c) acc[g][c] = (v4i){0, 0, 0, 0};

    ull m[2][4];
    v4i b[2][NCH];
    // prologue: load w=0 into buf 0
#pragma unroll
    for (int g = 0; g < 4; ++g) m[0][g] = mp[(size_t)0 * RT + g * 16];
    {
        const v4i* __restrict__ bp = (const v4i*)(Bq3 + (size_t)lane * 16);
#pragma unroll
        for (int c = 0; c < NCH; ++c) b[0][c] = bp[c * 64];
    }

#pragma unroll 2
    for (int w = 0; w < 32; ++w) {
        const int cur = w & 1, nxt = cur ^ 1;
        if (w < 31) {   // prefetch w+1 into nxt
#pragma unroll
            for (int g = 0; g < 4; ++g) m[nxt][g] = mp[(size_t)(w + 1) * RT + g * 16];
            const v4i* __restrict__ bp =
                (const v4i*)(Bq3 + (size_t)(w + 1) * 4096 + (size_t)lane * 16);
#pragma unroll
            for (int c = 0; c < NCH; ++c) b[nxt][c] = bp[c * 64];
        }
#pragma unroll
        for (int g = 0; g < 4; ++g) {
            unsigned s = (unsigned)(m[cur][g] >> sh) & 0xFFFFu;
            v4i a;
#pragma unroll
            for (int d = 0; d < 4; ++d)
                a[d] = (int)((((s >> (4 * d)) & 0xFu) * 0x00204081u) & 0x01010101u);
#pragma unroll
            for (int c = 0; c < NCH; ++c)
                acc[g][c] = __builtin_amdgcn_mfma_i32_16x16x64_i8(a, b[cur][c], acc[g][c], 0, 0, 0);
        }
    }

    if (li < OUT_DIM) {
#pragma unroll
        for (int g = 0; g < 4; ++g) {
#pragma unroll
            for (int rr = 0; rr < 4; ++rr) {
                long long V = (long long)acc[g][3][rr];
                V = (V << 8) + (long long)acc[g][2][rr];
                V = (V << 8) + (long long)acc[g][1][rr];
                V = (V << 8) + (long long)acc[g][0][rr];
                C3[(size_t)(row0 + g * 16 + lk * 4 + rr) * OUT_DIM + li] =
                    (double)V * 0x1p-31;
            }
        }
    }
}

// ---- LIF scan for a hidden layer; 8-deep load prefetch ----
__global__ __launch_bounds__(256) void lif_scan(
    const float* __restrict__ C, double* __restrict__ vstate,
    ull* __restrict__ SbitsT, int row_base, int Tl, int first)
{
    int g = blockIdx.x * 4 + (threadIdx.x >> 6);
    int lane = threadIdx.x & 63;
    int b = g >> 5;
    int ng = g & 31;
    int n = ng * 64 + lane;
    const float* __restrict__ Cp = C + (size_t)b * HID + n;
    ull* __restrict__ Sp = SbitsT + (size_t)ng * RT + row_base + b;
    double v = first ? 0.0 : vstate[(size_t)b * HID + n];
    int tl = 0;
    for (; tl + 8 <= Tl; tl += 8) {
        float cc[8];
#pragma unroll
        for (int i = 0; i < 8; ++i)
            cc[i] = Cp[(size_t)(tl + i) * (B * HID)];
#pragma unroll
        for (int i = 0; i < 8; ++i) {
            v = v * 0.9 + (double)cc[i];
            bool s = (v >= 1.0);
            if (s) v = 0.0;
            ull mask = __ballot(s);
            if (lane == 0) Sp[(size_t)(tl + i) * B] = mask;
        }
    }
    for (; tl < Tl; ++tl) {
        double c = (double)Cp[(size_t)tl * (B * HID)];
        v = v * 0.9 + c;
        bool s = (v >= 1.0);
        if (s) v = 0.0;
        ull mask = __ballot(s);
        if (lane == 0) Sp[(size_t)tl * B] = mask;
    }
    vstate[(size_t)b * HID + n] = v;
}

// ---- output LIF scan + rate accumulation; 4-deep prefetch ----
__global__ __launch_bounds__(256) void lif_out(
    const double* __restrict__ C3, double* __restrict__ vstate,
    int* __restrict__ cnt_state, float* __restrict__ out, int Tl, int first)
{
    int tid = blockIdx.x * 256 + threadIdx.x;
    if (tid >= B * OUT_DIM) return;
    int b = tid / OUT_DIM, o = tid % OUT_DIM;
    const double* __restrict__ Cp = C3 + (size_t)b * OUT_DIM + o;
    double v = first ? 0.0 : vstate[tid];
    int cnt = first ? 0 : cnt_state[tid];
    int tl = 0;
    for (; tl + 4 <= Tl; tl += 4) {
        double c0 = Cp[(size_t)(tl + 0) * (B * OUT_DIM)];
        double c1 = Cp[(size_t)(tl + 1) * (B * OUT_DIM)];
        double c2 = Cp[(size_t)(tl + 2) * (B * OUT_DIM)];
        double c3 = Cp[(size_t)(tl + 3) * (B * OUT_DIM)];
#pragma unroll
        for (int i = 0; i < 4; ++i) {
            double cc = (i == 0) ? c0 : (i == 1) ? c1 : (i == 2) ? c2 : c3;
            v = v * 0.9 + cc;
            if (v >= 1.0) { cnt++; v = 0.0; }
        }
    }
    for (; tl < Tl; ++tl) {
        double c = Cp[(size_t)tl * (B * OUT_DIM)];
        v = v * 0.9 + c;
        if (v >= 1.0) { cnt++; v = 0.0; }
    }
    vstate[tid] = v;
    cnt_state[tid] = cnt;
    out[tid] = (float)((double)cnt / (double)T_STEPS);
}

extern "C" void kernel_launch(void* const* d_in, const int* in_sizes, int n_in,
                              void* d_out, int out_size, void* d_ws, size_t ws_size,
                              hipStream_t stream) {
    const float* inp = (const float*)d_in[0];   // [256,1024,100]
    const float* wih = (const float*)d_in[1];   // [1024,2048]
    const float* whh = (const float*)d_in[2];   // [1,2048,2048]
    const float* who = (const float*)d_in[3];   // [2048,10]
    float* out = (float*)d_out;                 // [256,10]

    // ---- workspace layout ----
    unsigned char* p = (unsigned char*)d_ws;
    auto alloc = [&](size_t sz) -> void* {
        void* r = (void*)p;
        p += (sz + 255) & ~(size_t)255;
        return r;
    };
    signed char* Bq1 = (signed char*)alloc((size_t)NCH * HID * IN_DIM + 4096); // 8.4 MB
    signed char* Bq2 = (signed char*)alloc((size_t)NCH * HID * HID + 4096);    // 16.8 MB
    signed char* Bq3 = (signed char*)alloc((size_t)32 * 4096 + 4096);          // 132 KB
    ull* XbitsT = (ull*)alloc((size_t)16 * RT * 8);        // 3.3 MB
    ull* S1T    = (ull*)alloc((size_t)32 * RT * 8);        // 6.6 MB
    ull* S2T    = (ull*)alloc((size_t)32 * RT * 8);        // 6.6 MB
    double* v1 = (double*)alloc((size_t)B * HID * 8);
    double* v2 = (double*)alloc((size_t)B * HID * 8);
    double* vo = (double*)alloc((size_t)B * OUT_DIM * 8);
    int* cnts  = (int*)alloc((size_t)B * OUT_DIM * 4);

    size_t used = (size_t)(p - (unsigned char*)d_ws);
    size_t remain = (ws_size > used) ? (ws_size - used) : 0;
    size_t per_t = (size_t)B * HID * 4 + (size_t)B * OUT_DIM * 8 + 1024;
    int CH = (int)(remain / per_t);
    if (CH > T_STEPS) CH = T_STEPS;
    if (CH < 1) CH = 1;
    double* C3 = (double*)alloc((size_t)CH * B * OUT_DIM * 8);
    float* C   = (float*)alloc((size_t)CH * B * HID * 4);

    // ---- one-time prep ----
    cvt_w_i8<IN_DIM><<<((IN_DIM / 4) * HID + 255) / 256, 256, 0, stream>>>(wih, Bq1);
    cvt_w_i8<HID><<<((HID / 4) * HID + 255) / 256, 256, 0, stream>>>(whh, Bq2);
    cvt_who_i8<<<32, 256, 0, stream>>>(who, Bq3);
    bitpack_input<<<(B * (IN_DIM / 64)) / 4, 256, 0, stream>>>(inp, XbitsT);

    // ---- chunked time loop (CH=100 -> single chunk) ----
    for (int t0 = 0; t0 < T_STEPS; t0 += CH) {
        int L = T_STEPS - t0;
        if (L > CH) L = CH;
        int rows = L * B;            // multiple of 256
        int first = (t0 == 0) ? 1 : 0;

        // layer 1
        gemm_i8<IN_DIM><<<dim3(rows / 128, HID / 32), 256, 0, stream>>>(
            XbitsT, t0 * B, Bq1, C);
        lif_scan<<<(B * (HID / 64)) / 4, 256, 0, stream>>>(
            C, v1, S1T, t0 * B, L, first);

        // layer 2
        gemm_i8<HID><<<dim3(rows / 128, HID / 32), 256, 0, stream>>>(
            S1T, t0 * B, Bq2, C);
        lif_scan<<<(B * (HID / 64)) / 4, 256, 0, stream>>>(
            C, v2, S2T, t0 * B, L, first);

        // output layer
        gemm_out<<<rows / 256, 256, 0, stream>>>(S2T, t0 * B, Bq3, C3);
        lif_out<<<(B * OUT_DIM + 255) / 256, 256, 0, stream>>>(
            C3, vo, cnts, out, L, first);
    }
}

// Round 15
// 810.197 us; speedup vs baseline: 2.4957x; 1.2127x over previous
//
#include <hip/hip_runtime.h>
#include <hip/hip_bf16.h>

// SNN: B=256, IN=1024, HID=2048, OUT=10, T=100, decay=0.9, thr=1.0, reset=0.
// Layer-pipelined: GEMM1(all t) -> LIF scan -> GEMM2(all t) -> scan -> GEMM3 -> scan.
// Hidden GEMMs: i8 Ozaki split, 4 digit planes of round(w*2^31) (exact split;
// i32 MFMA accumulation exact).
// Round-29 = r24 VERBATIM (811us, the session best). Exploration record:
//  - r24 structure: r17 32x32-wave inner loop + 4-slot LDS ring (32KB) ->
//    4 blocks/CU, per-pair "s_waitcnt vmcnt(4); s_barrier" (drain this
//    pair's 4 stages, masks stay in flight). Measured: MfmaUtil 60,
//    LDS-issue pipe 76% busy (the binding resource), 0 conflicts, 0 spills.
//  - REFUTED alternatives (all within-session, root-caused):
//    r16/r18/r25-r28 M-reuse re-tiles (RMW writes / VGPR cliff / spills /
//    VALU expansion duplication 44% co-binding); r19 plane-split (VALU dup);
//    r20 SGB pipelining (-8%, T19 null-as-graft); r22 32x32x32 MFMA (4-deep
//    acc dep chains, -17%). r24 is the verified local optimum.
//  - Tail: gemm_out i8-MFMA + dbuf, lif_scan 8-deep prefetch, LDS bitpack,
//    fp32 C single chunk (CH=100), cvt_who_i8, 8KB-region cvt_w_i8 swizzle.

#define B 256
#define IN_DIM 1024
#define HID 2048
#define OUT_DIM 10
#define T_STEPS 100
#define NCH 4
#define RT (T_STEPS * B)   // 25600 global rows

typedef unsigned long long ull;
typedef int v4i __attribute__((ext_vector_type(4)));

// ---- weight fp32 -> 4 signed base-256 digit planes of round(w*2^31),
// swizzled to MFMA fragment order: region per (nb32, wb) = 8192 B, fragment
// (c,ct) at (c*2+ct)*1024, byte lane*16+jj, lane=lk*16+li,
// n = nb32*32 + ct*16 + li, k = wb*64 + lk*16 + jj.
// One thread: 4 consecutive k (same n) -> coalesced W loads, dword stores. ----
template<int K>
__global__ __launch_bounds__(256) void cvt_w_i8(
    const float* __restrict__ W, signed char* __restrict__ Bq)
{
    constexpr int WPR = K / 64;
    size_t id = (size_t)blockIdx.x * 256 + threadIdx.x;
    if (id >= (size_t)(K / 4) * HID) return;
    int n  = (int)(id % HID);
    int kg = (int)(id / HID);
    int k0 = kg * 4;                                  // jj multiple of 4
    signed char dig[4][4];                            // [plane][i]
#pragma unroll
    for (int i = 0; i < 4; ++i) {
        double w = (double)W[(size_t)(k0 + i) * HID + n];
        long long V = __double2ll_rn(w * 2147483648.0);   // w * 2^31
#pragma unroll
        for (int c = 0; c < 3; ++c) {
            int r = (int)(signed char)(V & 0xFF);     // balanced digit [-128,127]
            dig[c][i] = (signed char)r;
            V = (V - r) >> 8;
        }
        dig[3][i] = (signed char)V;                   // |V| <= ~70
    }
    int wb = k0 >> 6, lk = (k0 >> 4) & 3, jj = k0 & 15;
    int nb32 = n >> 5, ct = (n >> 4) & 1, li = n & 15;
    int lane = lk * 16 + li;
    size_t base = ((size_t)nb32 * WPR + wb) * 8192 + (size_t)lane * 16 + jj;
#pragma unroll
    for (int c = 0; c < 4; ++c) {
        int pc = c * 2 + ct;                          // c=3 -> 6+ct
        unsigned pk = (unsigned)(unsigned char)dig[c][0]
                    | ((unsigned)(unsigned char)dig[c][1] << 8)
                    | ((unsigned)(unsigned char)dig[c][2] << 16)
                    | ((unsigned)(unsigned char)dig[c][3] << 24);
        *reinterpret_cast<unsigned*>(Bq + base + (size_t)pc * 1024) = pk;
    }
}

// ---- output weights fp32 -> 4 i8 digit planes (exact), MFMA fragment order.
// Region per w (64 k): 4 planes x 1024 B; byte = plane*1024 + lane*16 + jj.
// k = w*64 + lk*16 + jj, col = li (cols 10..15 zero-padded). ----
__global__ __launch_bounds__(256) void cvt_who_i8(
    const float* __restrict__ who, signed char* __restrict__ Bq3)
{
    int id = blockIdx.x * 256 + threadIdx.x;      // 32 w x 64 lane x 4 jj-groups
    if (id >= 32 * 64 * 4) return;
    int jg = id & 3;
    int lane = (id >> 2) & 63;
    int w = id >> 8;
    int li = lane & 15, lk = lane >> 4;
    signed char dig[4][4];
#pragma unroll
    for (int i = 0; i < 4; ++i) {
        int jj = jg * 4 + i;
        int k = w * 64 + lk * 16 + jj;
        double x = (li < OUT_DIM) ? (double)who[(size_t)k * OUT_DIM + li] : 0.0;
        long long V = __double2ll_rn(x * 2147483648.0);
#pragma unroll
        for (int c = 0; c < 3; ++c) {
            int r = (int)(signed char)(V & 0xFF);
            dig[c][i] = (signed char)r;
            V = (V - r) >> 8;
        }
        dig[3][i] = (signed char)V;
    }
    size_t base = (size_t)w * 4096 + (size_t)lane * 16 + jg * 4;
#pragma unroll
    for (int c = 0; c < 4; ++c) {
        unsigned pk = (unsigned)(unsigned char)dig[c][0]
                    | ((unsigned)(unsigned char)dig[c][1] << 8)
                    | ((unsigned)(unsigned char)dig[c][2] << 16)
                    | ((unsigned)(unsigned char)dig[c][3] << 24);
        *reinterpret_cast<unsigned*>(Bq3 + base + (size_t)c * 1024) = pk;
    }
}

// ---- bit-pack input spikes -> TRANSPOSED XbitsT[w][t*256+b] ----
// Coalesced: each wave stages [64 i][<=32 t] fp32 tiles into LDS (flat copy,
// pad-33 row stride -> conflict-free column reads), then ballots from LDS.
__global__ __launch_bounds__(256) void bitpack_input(
    const float* __restrict__ inp, ull* __restrict__ XbitsT)
{
    __shared__ float sb[4][64][33];   // 33.8 KB
    const int wv = threadIdx.x >> 6;
    const int lane = threadIdx.x & 63;
    const int g = blockIdx.x * 4 + wv;
    const int b = g >> 4;
    const int ig = g & 15;
    const float* __restrict__ src = inp + ((size_t)b * IN_DIM + ig * 64) * T_STEPS;
    ull* __restrict__ dst = XbitsT + (size_t)ig * RT + b;

#pragma unroll
    for (int tc = 0; tc < 4; ++tc) {
        const int t0 = tc * 32;
        if (tc < 3) {
#pragma unroll
            for (int f4 = 0; f4 < 32; ++f4) {
                int f = f4 * 64 + lane;
                int ii = f >> 5, tt = f & 31;
                sb[wv][ii][tt] = src[ii * T_STEPS + t0 + tt];
            }
        } else {
#pragma unroll
            for (int f4 = 0; f4 < 4; ++f4) {
                int f = f4 * 64 + lane;
                int ii = f >> 2, tt = f & 3;
                sb[wv][ii][tt] = src[ii * T_STEPS + t0 + tt];
            }
        }
        __syncthreads();
        const int len = (tc < 3) ? 32 : 4;
        for (int tt = 0; tt < len; ++tt) {
            float v = sb[wv][lane][tt];
            ull m = __ballot(v > 0.5f);
            if (lane == 0) dst[(size_t)(t0 + tt) * B] = m;
        }
        __syncthreads();
    }
}

// ---- i8 Ozaki bit-GEMM: r17 loop, 4-slot ring, 4 blocks/CU ----
// Block: 128 rows x 32 cols, 4 waves (wave = 32 rows x 32 cols).
// Grid: x = rows/128, y = HID/32. row_base = t0*B (global row offset).
// Pair P consumes slots {2q,2q+1} (q=P&1), stages pair P+1 into {2-2q,3-2q}
// (consumed at P-1, barrier-protected). Per pair per wave: 4 stage + 4 mask
// loads; "s_waitcnt vmcnt(4); s_barrier" drains stages, leaves masks.
template<int K>
__global__ __launch_bounds__(256, 4) void gemm_i8(
    const ull* __restrict__ bitsT, int row_base,
    const signed char* __restrict__ Bq, float* __restrict__ C)
{
    constexpr int WPR = K / 64;          // 16 (L1) / 32 (L2)
    constexpr int NP  = WPR / 2;         // pairs: 8 / 16  (even)
    __shared__ __align__(16) signed char blds[4][8192];   // 32 KB -> 4 blk/CU

    const int tid = threadIdx.x;
    const int lane = tid & 63;
    const int wv = __builtin_amdgcn_readfirstlane(tid >> 6);
    const int row0 = blockIdx.x * 128;                    // local row base
    const int c0 = blockIdx.y * 32;
    const int li = lane & 15;
    const int lk = lane >> 4;
    const int sh = lk * 16;
    const int r0l = wv * 32;

    const signed char* __restrict__ bsrc = Bq + (size_t)blockIdx.y * WPR * 8192;
    const ull* __restrict__ m0p = bitsT + (row_base + row0 + r0l + li);
    const ull* __restrict__ m1p = m0p + 16;

    // stage B(w) into ring slot: 8 segments of 1 KB, 2 per wave (async to LDS)
    auto stage_b = [&](int w, int slot) {
        const signed char* src = bsrc + (size_t)w * 8192 + lane * 16;
        signed char* db = &blds[0][0] + slot * 8192;
        __builtin_amdgcn_global_load_lds(
            (const __attribute__((address_space(1))) unsigned int*)(src + wv * 1024),
            (__attribute__((address_space(3))) unsigned int*)(db + wv * 1024), 16, 0, 0);
        __builtin_amdgcn_global_load_lds(
            (const __attribute__((address_space(1))) unsigned int*)(src + (wv + 4) * 1024),
            (__attribute__((address_space(3))) unsigned int*)(db + (wv + 4) * 1024), 16, 0, 0);
    };

    // prologue: stage pair 0 (w=0,1 -> slots 0,1); masks for pairs 0,1 (w=0..3)
    stage_b(0, 0);
    stage_b(1, 1);
    ull r0[4], r1[4];
#pragma unroll
    for (int u = 0; u < 4; ++u) {
        r0[u] = m0p[(size_t)u * RT];
        r1[u] = m1p[(size_t)u * RT];
    }
    __syncthreads();   // full drain once (prologue)

    v4i acc[2][2][NCH];
#pragma unroll
    for (int g = 0; g < 2; ++g)
#pragma unroll
        for (int t = 0; t < 2; ++t)
#pragma unroll
            for (int c = 0; c < NCH; ++c) acc[g][t][c] = (v4i){0, 0, 0, 0};

    // Ring: pair P (parity q) reads slots {2q,2q+1}; stages w=2P+2,2P+3 into
    // {2-2q,3-2q} (consumed at P-1; the P-1 -> P barrier protects them).
    // Mask ring: slot u=w&3; refill with w+4 (consumed at pair P+2, stays in
    // flight across the vmcnt(4)). Tail stages/masks wrap to dummy-valid w.
#pragma unroll 1
    for (int p2 = 0; p2 < NP; p2 += 2) {  // 2 pairs per outer iter (idx const)
#pragma unroll
        for (int pp = 0; pp < 2; ++pp) {
            const int w0 = (p2 + pp) * 2;           // first w of pair
            const int q  = pp;                      // pair parity (p2 even)
            const int s0 = 2 * q, s1 = 2 * q + 1;   // consume slots
            const int tA = 2 - 2 * q, tB = 3 - 2 * q;   // stage slots
            const int u0 = 2 * q, u1 = 2 * q + 1;   // mask slots

            // stage NEXT pair + refill masks for pair P+2 FIRST
            int wn0 = w0 + 2; if (wn0 >= WPR) wn0 -= WPR;   // tail: dummy-valid
            int wn1 = w0 + 3; if (wn1 >= WPR) wn1 -= WPR;
            stage_b(wn0, tA);
            stage_b(wn1, tB);
            int wm0 = w0 + 4; if (wm0 >= WPR) wm0 -= WPR;
            int wm1 = w0 + 5; if (wm1 >= WPR) wm1 -= WPR;
            ull m00 = r0[u0], m01 = r1[u0];
            ull m10 = r0[u1], m11 = r1[u1];
            r0[u0] = m0p[(size_t)wm0 * RT];
            r1[u0] = m1p[(size_t)wm0 * RT];
            r0[u1] = m0p[(size_t)wm1 * RT];
            r1[u1] = m1p[(size_t)wm1 * RT];

            // ---- K-step A (w0), slot s0 ----
            {
                unsigned sa = (unsigned)(m00 >> sh) & 0xFFFFu;
                unsigned sb = (unsigned)(m01 >> sh) & 0xFFFFu;
                v4i a0, a1;
#pragma unroll
                for (int d = 0; d < 4; ++d) {
                    a0[d] = (int)((((sa >> (4 * d)) & 0xFu) * 0x00204081u) & 0x01010101u);
                    a1[d] = (int)((((sb >> (4 * d)) & 0xFu) * 0x00204081u) & 0x01010101u);
                }
                const signed char* bb = &blds[0][0] + s0 * 8192 + lane * 16;
                __builtin_amdgcn_s_setprio(1);
#pragma unroll
                for (int c = 0; c < NCH; ++c) {
#pragma unroll
                    for (int t = 0; t < 2; ++t) {
                        v4i b = *(const v4i*)(bb + (c * 2 + t) * 1024);
                        acc[0][t][c] = __builtin_amdgcn_mfma_i32_16x16x64_i8(a0, b, acc[0][t][c], 0, 0, 0);
                        acc[1][t][c] = __builtin_amdgcn_mfma_i32_16x16x64_i8(a1, b, acc[1][t][c], 0, 0, 0);
                    }
                }
                __builtin_amdgcn_s_setprio(0);
            }
            // ---- K-step B (w0+1), slot s1 ----
            {
                unsigned sa = (unsigned)(m10 >> sh) & 0xFFFFu;
                unsigned sb = (unsigned)(m11 >> sh) & 0xFFFFu;
                v4i a0, a1;
#pragma unroll
                for (int d = 0; d < 4; ++d) {
                    a0[d] = (int)((((sa >> (4 * d)) & 0xFu) * 0x00204081u) & 0x01010101u);
                    a1[d] = (int)((((sb >> (4 * d)) & 0xFu) * 0x00204081u) & 0x01010101u);
                }
                const signed char* bb = &blds[0][0] + s1 * 8192 + lane * 16;
                __builtin_amdgcn_s_setprio(1);
#pragma unroll
                for (int c = 0; c < NCH; ++c) {
#pragma unroll
                    for (int t = 0; t < 2; ++t) {
                        v4i b = *(const v4i*)(bb + (c * 2 + t) * 1024);
                        acc[0][t][c] = __builtin_amdgcn_mfma_i32_16x16x64_i8(a0, b, acc[0][t][c], 0, 0, 0);
                        acc[1][t][c] = __builtin_amdgcn_mfma_i32_16x16x64_i8(a1, b, acc[1][t][c], 0, 0, 0);
                    }
                }
                __builtin_amdgcn_s_setprio(0);
            }

            // drain this pair's 4 stages (next pair reads them after barrier);
            // the 4 mask refills (consumed at P+2) stay in flight
            __asm__ __volatile__("s_waitcnt vmcnt(4)\n\ts_barrier" ::: "memory");
        }
    }

    // exact recombination: V = (((S3<<8)+S2)<<8+S1)<<8+S0; |V| < 2^43.
#pragma unroll
    for (int g = 0; g < 2; ++g) {
#pragma unroll
        for (int t = 0; t < 2; ++t) {
#pragma unroll
            for (int r = 0; r < 4; ++r) {
                long long V = (long long)acc[g][t][3][r];
                V = (V << 8) + (long long)acc[g][t][2][r];
                V = (V << 8) + (long long)acc[g][t][1][r];
                V = (V << 8) + (long long)acc[g][t][0][r];
                C[(size_t)(row0 + r0l + g * 16 + lk * 4 + r) * HID + c0 + t * 16 + li] =
                    (float)((double)V * 0x1p-31);
            }
        }
    }
}

// ---- output bit-GEMM via i8 MFMA: 16-col tile (10 used), 4 exact planes ----
// Block: 256 rows, 4 waves (wave = 64 rows x 16 cols). Grid: rows/256.
// Latency-exposed (0.4 blk/CU) -> masks+B double-buffered one w ahead.
__global__ __launch_bounds__(256) void gemm_out(
    const ull* __restrict__ bitsT, int row_base,
    const signed char* __restrict__ Bq3, double* __restrict__ C3)
{
    const int lane = threadIdx.x & 63;
    const int wv = threadIdx.x >> 6;
    const int li = lane & 15;
    const int lk = lane >> 4;
    const int sh = lk * 16;
    const int row0 = blockIdx.x * 256 + wv * 64;
    const ull* __restrict__ mp = bitsT + (row_base + row0 + li);

    v4i acc[4][NCH];   // [row-group][plane]
#pragma unroll
    for (int g = 0; g < 4; ++g)
#pragma unroll
        for (int c = 0; c < NCH; ++c) acc[g][c] = (v4i){0, 0, 0, 0};

    ull m[2][4];
    v4i b[2][NCH];
    // prologue: load w=0 into buf 0
#pragma unroll
    for (int g = 0; g < 4; ++g) m[0][g] = mp[(size_t)0 * RT + g * 16];
    {
        const v4i* __restrict__ bp = (const v4i*)(Bq3 + (size_t)lane * 16);
#pragma unroll
        for (int c = 0; c < NCH; ++c) b[0][c] = bp[c * 64];
    }

#pragma unroll 2
    for (int w = 0; w < 32; ++w) {
        const int cur = w & 1, nxt = cur ^ 1;
        if (w < 31) {   // prefetch w+1 into nxt
#pragma unroll
            for (int g = 0; g < 4; ++g) m[nxt][g] = mp[(size_t)(w + 1) * RT + g * 16];
            const v4i* __restrict__ bp =
                (const v4i*)(Bq3 + (size_t)(w + 1) * 4096 + (size_t)lane * 16);
#pragma unroll
            for (int c = 0; c < NCH; ++c) b[nxt][c] = bp[c * 64];
        }
#pragma unroll
        for (int g = 0; g < 4; ++g) {
            unsigned s = (unsigned)(m[cur][g] >> sh) & 0xFFFFu;
            v4i a;
#pragma unroll
            for (int d = 0; d < 4; ++d)
                a[d] = (int)((((s >> (4 * d)) & 0xFu) * 0x00204081u) & 0x01010101u);
#pragma unroll
            for (int c = 0; c < NCH; ++c)
                acc[g][c] = __builtin_amdgcn_mfma_i32_16x16x64_i8(a, b[cur][c], acc[g][c], 0, 0, 0);
        }
    }

    if (li < OUT_DIM) {
#pragma unroll
        for (int g = 0; g < 4; ++g) {
#pragma unroll
            for (int rr = 0; rr < 4; ++rr) {
                long long V = (long long)acc[g][3][rr];
                V = (V << 8) + (long long)acc[g][2][rr];
                V = (V << 8) + (long long)acc[g][1][rr];
                V = (V << 8) + (long long)acc[g][0][rr];
                C3[(size_t)(row0 + g * 16 + lk * 4 + rr) * OUT_DIM + li] =
                    (double)V * 0x1p-31;
            }
        }
    }
}

// ---- LIF scan for a hidden layer; 8-deep load prefetch ----
__global__ __launch_bounds__(256) void lif_scan(
    const float* __restrict__ C, double* __restrict__ vstate,
    ull* __restrict__ SbitsT, int row_base, int Tl, int first)
{
    int g = blockIdx.x * 4 + (threadIdx.x >> 6);
    int lane = threadIdx.x & 63;
    int b = g >> 5;
    int ng = g & 31;
    int n = ng * 64 + lane;
    const float* __restrict__ Cp = C + (size_t)b * HID + n;
    ull* __restrict__ Sp = SbitsT + (size_t)ng * RT + row_base + b;
    double v = first ? 0.0 : vstate[(size_t)b * HID + n];
    int tl = 0;
    for (; tl + 8 <= Tl; tl += 8) {
        float cc[8];
#pragma unroll
        for (int i = 0; i < 8; ++i)
            cc[i] = Cp[(size_t)(tl + i) * (B * HID)];
#pragma unroll
        for (int i = 0; i < 8; ++i) {
            v = v * 0.9 + (double)cc[i];
            bool s = (v >= 1.0);
            if (s) v = 0.0;
            ull mask = __ballot(s);
            if (lane == 0) Sp[(size_t)(tl + i) * B] = mask;
        }
    }
    for (; tl < Tl; ++tl) {
        double c = (double)Cp[(size_t)tl * (B * HID)];
        v = v * 0.9 + c;
        bool s = (v >= 1.0);
        if (s) v = 0.0;
        ull mask = __ballot(s);
        if (lane == 0) Sp[(size_t)tl * B] = mask;
    }
    vstate[(size_t)b * HID + n] = v;
}

// ---- output LIF scan + rate accumulation; 4-deep prefetch ----
__global__ __launch_bounds__(256) void lif_out(
    const double* __restrict__ C3, double* __restrict__ vstate,
    int* __restrict__ cnt_state, float* __restrict__ out, int Tl, int first)
{
    int tid = blockIdx.x * 256 + threadIdx.x;
    if (tid >= B * OUT_DIM) return;
    int b = tid / OUT_DIM, o = tid % OUT_DIM;
    const double* __restrict__ Cp = C3 + (size_t)b * OUT_DIM + o;
    double v = first ? 0.0 : vstate[tid];
    int cnt = first ? 0 : cnt_state[tid];
    int tl = 0;
    for (; tl + 4 <= Tl; tl += 4) {
        double c0 = Cp[(size_t)(tl + 0) * (B * OUT_DIM)];
        double c1 = Cp[(size_t)(tl + 1) * (B * OUT_DIM)];
        double c2 = Cp[(size_t)(tl + 2) * (B * OUT_DIM)];
        double c3 = Cp[(size_t)(tl + 3) * (B * OUT_DIM)];
#pragma unroll
        for (int i = 0; i < 4; ++i) {
            double cc = (i == 0) ? c0 : (i == 1) ? c1 : (i == 2) ? c2 : c3;
            v = v * 0.9 + cc;
            if (v >= 1.0) { cnt++; v = 0.0; }
        }
    }
    for (; tl < Tl; ++tl) {
        double c = Cp[(size_t)tl * (B * OUT_DIM)];
        v = v * 0.9 + c;
        if (v >= 1.0) { cnt++; v = 0.0; }
    }
    vstate[tid] = v;
    cnt_state[tid] = cnt;
    out[tid] = (float)((double)cnt / (double)T_STEPS);
}

extern "C" void kernel_launch(void* const* d_in, const int* in_sizes, int n_in,
                              void* d_out, int out_size, void* d_ws, size_t ws_size,
                              hipStream_t stream) {
    const float* inp = (const float*)d_in[0];   // [256,1024,100]
    const float* wih = (const float*)d_in[1];   // [1024,2048]
    const float* whh = (const float*)d_in[2];   // [1,2048,2048]
    const float* who = (const float*)d_in[3];   // [2048,10]
    float* out = (float*)d_out;                 // [256,10]

    // ---- workspace layout ----
    unsigned char* p = (unsigned char*)d_ws;
    auto alloc = [&](size_t sz) -> void* {
        void* r = (void*)p;
        p += (sz + 255) & ~(size_t)255;
        return r;
    };
    signed char* Bq1 = (signed char*)alloc((size_t)NCH * HID * IN_DIM + 4096); // 8.4 MB
    signed char* Bq2 = (signed char*)alloc((size_t)NCH * HID * HID + 4096);    // 16.8 MB
    signed char* Bq3 = (signed char*)alloc((size_t)32 * 4096 + 4096);          // 132 KB
    ull* XbitsT = (ull*)alloc((size_t)16 * RT * 8);        // 3.3 MB
    ull* S1T    = (ull*)alloc((size_t)32 * RT * 8);        // 6.6 MB
    ull* S2T    = (ull*)alloc((size_t)32 * RT * 8);        // 6.6 MB
    double* v1 = (double*)alloc((size_t)B * HID * 8);
    double* v2 = (double*)alloc((size_t)B * HID * 8);
    double* vo = (double*)alloc((size_t)B * OUT_DIM * 8);
    int* cnts  = (int*)alloc((size_t)B * OUT_DIM * 4);

    size_t used = (size_t)(p - (unsigned char*)d_ws);
    size_t remain = (ws_size > used) ? (ws_size - used) : 0;
    size_t per_t = (size_t)B * HID * 4 + (size_t)B * OUT_DIM * 8 + 1024;
    int CH = (int)(remain / per_t);
    if (CH > T_STEPS) CH = T_STEPS;
    if (CH < 1) CH = 1;
    double* C3 = (double*)alloc((size_t)CH * B * OUT_DIM * 8);
    float* C   = (float*)alloc((size_t)CH * B * HID * 4);

    // ---- one-time prep ----
    cvt_w_i8<IN_DIM><<<((IN_DIM / 4) * HID + 255) / 256, 256, 0, stream>>>(wih, Bq1);
    cvt_w_i8<HID><<<((HID / 4) * HID + 255) / 256, 256, 0, stream>>>(whh, Bq2);
    cvt_who_i8<<<32, 256, 0, stream>>>(who, Bq3);
    bitpack_input<<<(B * (IN_DIM / 64)) / 4, 256, 0, stream>>>(inp, XbitsT);

    // ---- chunked time loop (CH=100 -> single chunk) ----
    for (int t0 = 0; t0 < T_STEPS; t0 += CH) {
        int L = T_STEPS - t0;
        if (L > CH) L = CH;
        int rows = L * B;            // multiple of 256
        int first = (t0 == 0) ? 1 : 0;

        // layer 1
        gemm_i8<IN_DIM><<<dim3(rows / 128, HID / 32), 256, 0, stream>>>(
            XbitsT, t0 * B, Bq1, C);
        lif_scan<<<(B * (HID / 64)) / 4, 256, 0, stream>>>(
            C, v1, S1T, t0 * B, L, first);

        // layer 2
        gemm_i8<HID><<<dim3(rows / 128, HID / 32), 256, 0, stream>>>(
            S1T, t0 * B, Bq2, C);
        lif_scan<<<(B * (HID / 64)) / 4, 256, 0, stream>>>(
            C, v2, S2T, t0 * B, L, first);

        // output layer
        gemm_out<<<rows / 256, 256, 0, stream>>>(S2T, t0 * B, Bq3, C3);
        lif_out<<<(B * OUT_DIM + 255) / 256, 256, 0, stream>>>(
            C3, vo, cnts, out, L, first);
    }
}